// Round 1
// baseline (1275.125 us; speedup 1.0000x reference)
//
#include <hip/hip_runtime.h>
#include <math.h>

#define N_NODES 100000
#define N_EDGES 800000
#define NODE_IN 32
#define EDGE_DIM 84
#define HIDDEN 24
#define HEAD_HIDDEN 20
#define CAT_DIM 132
#define LN_EPS 1e-5f

typedef __attribute__((ext_vector_type(8))) short short8;
typedef __attribute__((ext_vector_type(4))) float f32x4;
typedef unsigned int uint;
typedef unsigned short ushort;

__device__ __forceinline__ float gelu_exact(float x) {
    return 0.5f * x * (1.0f + erff(x * 0.70710678118654752f));
}
__device__ __forceinline__ ushort f2bf(float f) {
    union { float f; uint u; } c; c.f = f;
    uint u = c.u;
    return (ushort)((u + 0x7fffu + ((u >> 16) & 1u)) >> 16);
}
__device__ __forceinline__ float bf2f(ushort s) {
    union { uint u; float f; } c; c.u = ((uint)s) << 16; return c.f;
}

// ---------------- weight pre-pack to MFMA-fragment-major bf16 ----------------
// frag element (lane, j) = W[kt*32 + (lane>>4)*8 + j][nt*16 + (lane&15)], zero-padded.
// regions (frags of 512 bf16): pe_w1 2L*30 | pe_w2 2L*18 | pv_w1 2L*10 | pv_w2 2L*2
__global__ void k_prep_w(const float* __restrict__ pe_w1, const float* __restrict__ pe_w2,
                         const float* __restrict__ pv_w1, const float* __restrict__ pv_w2,
                         ushort* __restrict__ wp) {
    int idx = blockIdx.x * 256 + threadIdx.x;        // < 61440
    int j = idx & 7;
    int lane = (idx >> 3) & 63;
    int frag = idx >> 9;                             // 0..119
    int kq = (lane >> 4) * 8 + j;
    int n15 = lane & 15;
    float v = 0.f;
    if (frag < 60) {                                 // pe_w1: [L][5kt][6nt]
        int l = frag / 30, f = frag % 30;
        int kt = f / 6, nt = f % 6;
        int k = kt * 32 + kq, n = nt * 16 + n15;
        if (k < CAT_DIM && n < EDGE_DIM) v = pe_w1[(l * CAT_DIM + k) * EDGE_DIM + n];
    } else if (frag < 96) {                          // pe_w2: [L][3kt][6nt]
        int f2 = frag - 60; int l = f2 / 18, f = f2 % 18;
        int kt = f / 6, nt = f % 6;
        int k = kt * 32 + kq, n = nt * 16 + n15;
        if (k < EDGE_DIM && n < EDGE_DIM) v = pe_w2[(l * EDGE_DIM + k) * EDGE_DIM + n];
    } else if (frag < 116) {                         // pv_w1: [L][5kt][2nt]
        int f2 = frag - 96; int l = f2 / 10, f = f2 % 10;
        int kt = f / 2, nt = f % 2;
        int k = kt * 32 + kq, n = nt * 16 + n15;
        if (k < CAT_DIM && n < HIDDEN) v = pv_w1[(l * CAT_DIM + k) * HIDDEN + n];
    } else {                                         // pv_w2: [L][1kt][2nt]
        int f2 = frag - 116; int l = f2 / 2, nt = f2 % 2;
        int k = kq, n = nt * 16 + n15;
        if (k < HIDDEN && n < HIDDEN) v = pv_w2[(l * HIDDEN + k) * HIDDEN + n];
    }
    wp[idx] = f2bf(v);
}

// ---------------- node input projection + intrinsic head ----------------
__global__ void k_node_in(const float* __restrict__ x,
                          const float* __restrict__ node_w, const float* __restrict__ node_b,
                          const float* __restrict__ ih_w1, const float* __restrict__ ih_b1,
                          const float* __restrict__ ih_w2, const float* __restrict__ ih_b2,
                          float* __restrict__ h, ushort* __restrict__ h_bf,
                          float* __restrict__ intr) {
    int n = blockIdx.x * blockDim.x + threadIdx.x;
    if (n >= N_NODES) return;
    float xv[NODE_IN];
    const float4* xp = (const float4*)(x + (size_t)n * NODE_IN);
#pragma unroll
    for (int i = 0; i < NODE_IN / 4; i++) {
        float4 v = xp[i];
        xv[4*i+0] = v.x; xv[4*i+1] = v.y; xv[4*i+2] = v.z; xv[4*i+3] = v.w;
    }
    float hv[HIDDEN];
#pragma unroll
    for (int j = 0; j < HIDDEN; j++) hv[j] = node_b[j];
    for (int k = 0; k < NODE_IN; k++) {
        float xk = xv[k];
#pragma unroll
        for (int j = 0; j < HIDDEN; j++) hv[j] = fmaf(xk, node_w[k * HIDDEN + j], hv[j]);
    }
#pragma unroll
    for (int j = 0; j < HIDDEN; j++) {
        h[(size_t)n * HIDDEN + j] = hv[j];
        h_bf[(size_t)n * HIDDEN + j] = f2bf(hv[j]);
    }
    float acc = ih_b2[0];
    for (int j = 0; j < HEAD_HIDDEN; j++) {
        float t = ih_b1[j];
#pragma unroll
        for (int k = 0; k < HIDDEN; k++) t = fmaf(hv[k], ih_w1[k * HEAD_HIDDEN + j], t);
        acc = fmaf(gelu_exact(t), ih_w2[j], acc);
    }
    intr[n] = acc;
}

__global__ void k_counts(const int* __restrict__ ei, int* __restrict__ cnt) {
    int e = blockIdx.x * blockDim.x + threadIdx.x;
    if (e >= N_EDGES) return;
    atomicAdd(&cnt[ei[N_EDGES + e]], 1);
}

// A-fragment gather from global: cat layout [src h 0-23 | dst h 24-47 | e 48-143 | pad].
// Chunks beyond real data are clamped to a safe address; zero-padded weights kill them.
__device__ __forceinline__ short8 ld_catA(const ushort* __restrict__ h_bf,
                                          const float* __restrict__ eattr,
                                          const ushort* __restrict__ e_bf,
                                          int src, int dst, long rowg, int c) {
    if (c < 48) {
        const ushort* p = (c < 24) ? h_bf + (size_t)src * 24 + c
                                   : h_bf + (size_t)dst * 24 + (c - 24);
        return *(const short8*)p;
    }
    int ec = c - 48;
    if (eattr) {
        const float* q = eattr + rowg * 84;
        f32x4 lo = *(const f32x4*)(q + ((ec <= 80) ? ec : 0));
        f32x4 hi = *(const f32x4*)(q + ((ec <= 76) ? (ec + 4) : 0));
        short8 r;
        r[0] = (short)f2bf(lo[0]); r[1] = (short)f2bf(lo[1]);
        r[2] = (short)f2bf(lo[2]); r[3] = (short)f2bf(lo[3]);
        r[4] = (short)f2bf(hi[0]); r[5] = (short)f2bf(hi[1]);
        r[6] = (short)f2bf(hi[2]); r[7] = (short)f2bf(hi[3]);
        return r;
    }
    return *(const short8*)(e_bf + rowg * 96 + ((ec < 96) ? ec : 0));
}

// Same gather but e part comes from LDS (e_new), block-local row.
__device__ __forceinline__ short8 ld_catV(const ushort* __restrict__ h_bf,
                                          const ushort* __restrict__ sT,
                                          int src, int dst, int rowL, int c) {
    if (c < 48) {
        const ushort* p = (c < 24) ? h_bf + (size_t)src * 24 + c
                                   : h_bf + (size_t)dst * 24 + (c - 24);
        return *(const short8*)p;
    }
    int ec = c - 48;
    return *(const short8*)(sT + rowL * 104 + ((ec < 96) ? ec : 0));
}

// ---------------- fused per-layer edge kernel: phi_e + LN + phi_v + scatter ----------------
// 128 edges/block, 8 waves (16 rows each, wave-private) -> 2 barriers total.
// LDS 37888B * 4 blocks/CU = 151552 <= 160K; 4 blocks * 8 waves = 32 waves/CU = 100%.
__global__ __launch_bounds__(512, 8)
void k_edge_fused(const ushort* __restrict__ h_bf,
                  const float* __restrict__ eattr,   // layer0 edge_attr fp32, else null
                  ushort* __restrict__ e_bf,         // padded 96-col bf16; in (L>0) / out
                  const int* __restrict__ ei,
                  const ushort* __restrict__ w1f, const ushort* __restrict__ w2f,
                  const ushort* __restrict__ v1f, const ushort* __restrict__ v2f,
                  const float* __restrict__ b1, const float* __restrict__ b2,
                  const float* __restrict__ g, const float* __restrict__ bb,
                  const float* __restrict__ vb1, const float* __restrict__ vb2,
                  float* __restrict__ agg, int store_e) {
    __shared__ __align__(16) ushort sT[128 * 104];   // t1 then e_new, pitch 104
    __shared__ __align__(16) ushort sTV[128 * 40];   // t_v, pitch 40
    __shared__ int s_idx[256];

    const int tid = threadIdx.x;
    const int e0 = blockIdx.x * 128;
    if (tid < 256) s_idx[tid] = ei[(size_t)(tid >> 7) * N_EDGES + e0 + (tid & 127)];
    __syncthreads();

    const int lane = tid & 63, wave = tid >> 6;      // wave 0..7
    const int quad = lane >> 4, l15 = lane & 15;
    const int cbase = quad * 8;
    const int rA = wave * 16 + l15;                  // single A-frag row per wave
    const int srcA = s_idx[rA], dstA = s_idx[128 + rA];

    // ---- GEMM1: t1 = cat @ w1 ----
    f32x4 acc[6];
#pragma unroll
    for (int nt = 0; nt < 6; nt++) acc[nt] = (f32x4)0.f;
#pragma unroll
    for (int kt = 0; kt < 5; kt++) {
        int c = kt * 32 + cbase;
        short8 a = ld_catA(h_bf, eattr, e_bf, srcA, dstA, (long)(e0 + rA), c);
        const short8* bp = (const short8*)w1f + kt * 6 * 64 + lane;
#pragma unroll
        for (int nt = 0; nt < 6; nt++) {
            short8 b = bp[nt * 64];
            acc[nt] = __builtin_amdgcn_mfma_f32_16x16x32_bf16(a, b, acc[nt], 0, 0, 0);
        }
    }
    // gelu -> sT (wave-private rows; pad cols come out exactly 0)
#pragma unroll
    for (int nt = 0; nt < 6; nt++) {
        int col = nt * 16 + l15;
        float bv = (col < EDGE_DIM) ? b1[col] : 0.f;
#pragma unroll
        for (int r = 0; r < 4; r++) {
            int row = wave * 16 + quad * 4 + r;
            sT[row * 104 + col] = f2bf(gelu_exact(acc[nt][r] + bv));
        }
    }

    // ---- GEMM2: t1 @ w2 (rows wave-private, no barrier) ----
    f32x4 acc2[6];
#pragma unroll
    for (int nt = 0; nt < 6; nt++) acc2[nt] = (f32x4)0.f;
#pragma unroll
    for (int kt = 0; kt < 3; kt++) {
        short8 a = *(const short8*)(sT + (size_t)rA * 104 + kt * 32 + cbase);
        const short8* bp = (const short8*)w2f + kt * 6 * 64 + lane;
#pragma unroll
        for (int nt = 0; nt < 6; nt++) {
            short8 b = bp[nt * 64];
            acc2[nt] = __builtin_amdgcn_mfma_f32_16x16x32_bf16(a, b, acc2[nt], 0, 0, 0);
        }
    }

    // ---- bias + residual + LayerNorm -> e_new (bf16) back into sT ----
#pragma unroll
    for (int r = 0; r < 4; r++) {
        int row = wave * 16 + quad * 4 + r;
        long rg = e0 + row;
        float vv[6];
        float ss = 0.f, qq = 0.f;
#pragma unroll
        for (int nt = 0; nt < 6; nt++) {
            int col = nt * 16 + l15;
            float v = 0.f;
            if (col < EDGE_DIM) {
                v = acc2[nt][r] + b2[col];
                v += eattr ? eattr[rg * 84 + col] : bf2f(e_bf[rg * 96 + col]);
            }
            vv[nt] = v; ss += v; qq = fmaf(v, v, qq);
        }
        ss += __shfl_xor(ss, 1); ss += __shfl_xor(ss, 2);
        ss += __shfl_xor(ss, 4); ss += __shfl_xor(ss, 8);
        qq += __shfl_xor(qq, 1); qq += __shfl_xor(qq, 2);
        qq += __shfl_xor(qq, 4); qq += __shfl_xor(qq, 8);
        float mean = ss * (1.f / EDGE_DIM);
        float var  = qq * (1.f / EDGE_DIM) - mean * mean;
        float rstd = rsqrtf(var + LN_EPS);
#pragma unroll
        for (int nt = 0; nt < 6; nt++) {
            int col = nt * 16 + l15;
            if (col < EDGE_DIM)
                sT[row * 104 + col] = f2bf((vv[nt] - mean) * rstd * g[col] + bb[col]);
        }
    }

    // ---- GEMM_V1: [h_src|h_dst|e_new] @ v1 (e from sT, wave-private rows) ----
    f32x4 av[2];
#pragma unroll
    for (int nt = 0; nt < 2; nt++) av[nt] = (f32x4)0.f;
#pragma unroll
    for (int kt = 0; kt < 5; kt++) {
        int c = kt * 32 + cbase;
        short8 a = ld_catV(h_bf, sT, srcA, dstA, rA, c);
        const short8* bp = (const short8*)v1f + kt * 2 * 64 + lane;
#pragma unroll
        for (int nt = 0; nt < 2; nt++) {
            short8 b = bp[nt * 64];
            av[nt] = __builtin_amdgcn_mfma_f32_16x16x32_bf16(a, b, av[nt], 0, 0, 0);
        }
    }
    // gelu -> sTV
#pragma unroll
    for (int nt = 0; nt < 2; nt++) {
        int col = nt * 16 + l15;
        float bv = (col < HIDDEN) ? vb1[col] : 0.f;
#pragma unroll
        for (int r = 0; r < 4; r++) {
            int row = wave * 16 + quad * 4 + r;
            sTV[row * 40 + col] = f2bf(gelu_exact(av[nt][r] + bv));
        }
    }

    // ---- GEMM_V2: t_v @ v2 ----
    f32x4 av2[2];
#pragma unroll
    for (int nt = 0; nt < 2; nt++) av2[nt] = (f32x4)0.f;
    {
        short8 a = *(const short8*)(sTV + (size_t)rA * 40 + cbase);
        const short8* bp = (const short8*)v2f + lane;
#pragma unroll
        for (int nt = 0; nt < 2; nt++) {
            short8 b = bp[nt * 64];
            av2[nt] = __builtin_amdgcn_mfma_f32_16x16x32_bf16(a, b, av2[nt], 0, 0, 0);
        }
    }
    // scatter-add m into agg
#pragma unroll
    for (int nt = 0; nt < 2; nt++) {
        int col = nt * 16 + l15;
        if (col < HIDDEN) {
            float bv = vb2[col];
#pragma unroll
            for (int r = 0; r < 4; r++) {
                int row = wave * 16 + quad * 4 + r;
                int d = s_idx[128 + row];
                atomicAdd(&agg[(size_t)d * HIDDEN + col], av2[nt][r] + bv);
            }
        }
    }

    // ---- store e_new (padded 96-col bf16), skipped on last layer ----
    if (store_e) {
        __syncthreads();
        const uint* sTu = (const uint*)sT;           // pitch 52 dwords
        uint* dst32 = (uint*)e_bf + (size_t)e0 * 48;
#pragma unroll
        for (int i = 0; i < 12; i++) {
            int idx = tid + 512 * i;                 // < 6144
            int row = idx / 48, d = idx - row * 48;
            dst32[idx] = sTu[row * 52 + d];
        }
    }
}

// ---------------- node update: h = LN(h + agg/counts) ----------------
__global__ void k_node_up(float* __restrict__ h, ushort* __restrict__ h_bf,
                          const float* __restrict__ agg,
                          const int* __restrict__ cnt,
                          const float* __restrict__ g, const float* __restrict__ b) {
    int n = blockIdx.x * blockDim.x + threadIdx.x;
    if (n >= N_NODES) return;
    int c = cnt[n]; if (c < 1) c = 1;
    float inv = 1.0f / (float)c;
    float v[HIDDEN];
    float s = 0.f;
#pragma unroll
    for (int j = 0; j < HIDDEN; j++) {
        v[j] = h[(size_t)n * HIDDEN + j] + agg[(size_t)n * HIDDEN + j] * inv;
        s += v[j];
    }
    float mean = s * (1.f / HIDDEN);
    float sq = 0.f;
#pragma unroll
    for (int j = 0; j < HIDDEN; j++) { float d = v[j] - mean; sq = fmaf(d, d, sq); }
    float rstd = rsqrtf(sq * (1.f / HIDDEN) + LN_EPS);
#pragma unroll
    for (int j = 0; j < HIDDEN; j++) {
        float o = (v[j] - mean) * rstd * g[j] + b[j];
        h[(size_t)n * HIDDEN + j] = o;
        h_bf[(size_t)n * HIDDEN + j] = f2bf(o);
    }
}

// ---------------- final: out = mu + intrinsic + context(h) ----------------
__global__ void k_final(const float* __restrict__ h, const float* __restrict__ intr,
                        const float* __restrict__ ch_w1, const float* __restrict__ ch_b1,
                        const float* __restrict__ ch_w2, const float* __restrict__ ch_b2,
                        const float* __restrict__ mu, float* __restrict__ out) {
    int n = blockIdx.x * blockDim.x + threadIdx.x;
    if (n >= N_NODES) return;
    float hv[HIDDEN];
#pragma unroll
    for (int j = 0; j < HIDDEN; j++) hv[j] = h[(size_t)n * HIDDEN + j];
    float acc = ch_b2[0];
    for (int j = 0; j < HEAD_HIDDEN; j++) {
        float t = ch_b1[j];
#pragma unroll
        for (int k = 0; k < HIDDEN; k++) t = fmaf(hv[k], ch_w1[k * HEAD_HIDDEN + j], t);
        acc = fmaf(gelu_exact(t), ch_w2[j], acc);
    }
    out[n] = mu[0] + intr[n] + acc;
}

extern "C" void kernel_launch(void* const* d_in, const int* in_sizes, int n_in,
                              void* d_out, int out_size, void* d_ws, size_t ws_size,
                              hipStream_t stream) {
    const float* x        = (const float*)d_in[0];
    const float* edge_attr= (const float*)d_in[1];
    const float* node_w   = (const float*)d_in[2];
    const float* node_b   = (const float*)d_in[3];
    const float* ih_w1    = (const float*)d_in[4];
    const float* ih_b1    = (const float*)d_in[5];
    const float* ih_w2    = (const float*)d_in[6];
    const float* ih_b2    = (const float*)d_in[7];
    const float* pe_w1    = (const float*)d_in[8];
    const float* pe_b1    = (const float*)d_in[9];
    const float* pe_w2    = (const float*)d_in[10];
    const float* pe_b2    = (const float*)d_in[11];
    const float* pv_w1    = (const float*)d_in[12];
    const float* pv_b1    = (const float*)d_in[13];
    const float* pv_w2    = (const float*)d_in[14];
    const float* pv_b2    = (const float*)d_in[15];
    const float* ne_g     = (const float*)d_in[16];
    const float* ne_b     = (const float*)d_in[17];
    const float* nv_g     = (const float*)d_in[18];
    const float* nv_b     = (const float*)d_in[19];
    const float* ch_w1    = (const float*)d_in[20];
    const float* ch_b1    = (const float*)d_in[21];
    const float* ch_w2    = (const float*)d_in[22];
    const float* ch_b2    = (const float*)d_in[23];
    const float* mu       = (const float*)d_in[24];
    const int*   ei       = (const int*)d_in[25];

    char* ws = (char*)d_ws;
    float*  h    = (float*)ws;  ws += (size_t)N_NODES * HIDDEN * 4;
    float*  agg  = (float*)ws;  ws += (size_t)N_NODES * HIDDEN * 4;
    float*  intr = (float*)ws;  ws += (size_t)N_NODES * 4;
    int*    cnt  = (int*)ws;    ws += (size_t)N_NODES * 4;
    ushort* h_bf = (ushort*)ws; ws += (size_t)N_NODES * HIDDEN * 2;
    ushort* wp   = (ushort*)ws; ws += (size_t)61440 * 2;
    ws = (char*)(((size_t)ws + 255) & ~(size_t)255);
    ushort* e_bf = (ushort*)ws; ws += (size_t)N_EDGES * 96 * 2;   // padded 96 cols

    const ushort* we1[2] = { wp + 0 * 15360, wp + 1 * 15360 };
    const ushort* we2[2] = { wp + 30720 + 0 * 9216, wp + 30720 + 1 * 9216 };
    const ushort* wv1[2] = { wp + 49152 + 0 * 5120, wp + 49152 + 1 * 5120 };
    const ushort* wv2[2] = { wp + 59392 + 0 * 1024, wp + 59392 + 1 * 1024 };

    hipMemsetAsync(cnt, 0, (size_t)N_NODES * 4, stream);
    k_prep_w<<<240, 256, 0, stream>>>(pe_w1, pe_w2, pv_w1, pv_w2, wp);
    k_counts<<<(N_EDGES + 255) / 256, 256, 0, stream>>>(ei, cnt);
    k_node_in<<<(N_NODES + 255) / 256, 256, 0, stream>>>(
        x, node_w, node_b, ih_w1, ih_b1, ih_w2, ih_b2, h, h_bf, intr);

    const int eb = N_EDGES / 128;   // 6250, exact
    for (int L = 0; L < 2; L++) {
        hipMemsetAsync(agg, 0, (size_t)N_NODES * HIDDEN * 4, stream);
        k_edge_fused<<<eb, 512, 0, stream>>>(
            h_bf, (L == 0) ? edge_attr : (const float*)nullptr, e_bf, ei,
            we1[L], we2[L], wv1[L], wv2[L],
            pe_b1 + (size_t)L * EDGE_DIM, pe_b2 + (size_t)L * EDGE_DIM,
            ne_g + (size_t)L * EDGE_DIM, ne_b + (size_t)L * EDGE_DIM,
            pv_b1 + (size_t)L * HIDDEN, pv_b2 + (size_t)L * HIDDEN,
            agg, (L == 0) ? 1 : 0);
        k_node_up<<<(N_NODES + 255) / 256, 256, 0, stream>>>(
            h, h_bf, agg, cnt, nv_g + (size_t)L * HIDDEN, nv_b + (size_t)L * HIDDEN);
    }
    k_final<<<(N_NODES + 255) / 256, 256, 0, stream>>>(
        h, intr, ch_w1, ch_b1, ch_w2, ch_b2, mu, (float*)d_out);
}

// Round 2
// 1137.291 us; speedup vs baseline: 1.1212x; 1.1212x over previous
//
#include <hip/hip_runtime.h>
#include <math.h>

#define N_NODES 100000
#define N_EDGES 800000
#define NODE_IN 32
#define EDGE_DIM 84
#define HIDDEN 24
#define HEAD_HIDDEN 20
#define CAT_DIM 132
#define LN_EPS 1e-5f

typedef __attribute__((ext_vector_type(8))) short short8;
typedef __attribute__((ext_vector_type(4))) float f32x4;
typedef unsigned int uint;
typedef unsigned short ushort;

__device__ __forceinline__ float gelu_exact(float x) {
    return 0.5f * x * (1.0f + erff(x * 0.70710678118654752f));
}
__device__ __forceinline__ ushort f2bf(float f) {
    union { float f; uint u; } c; c.f = f;
    uint u = c.u;
    return (ushort)((u + 0x7fffu + ((u >> 16) & 1u)) >> 16);
}
__device__ __forceinline__ float bf2f(ushort s) {
    union { uint u; float f; } c; c.u = ((uint)s) << 16; return c.f;
}

// ---------------- weight pre-pack to MFMA-fragment-major bf16 ----------------
// frag element (lane, j) = W[kt*32 + (lane>>4)*8 + j][nt*16 + (lane&15)], zero-padded.
// regions (frags of 512 bf16): pe_w1 2L*30 | pe_w2 2L*18 | pv_w1 2L*10 | pv_w2 2L*2
__global__ void k_prep_w(const float* __restrict__ pe_w1, const float* __restrict__ pe_w2,
                         const float* __restrict__ pv_w1, const float* __restrict__ pv_w2,
                         ushort* __restrict__ wp) {
    int idx = blockIdx.x * 256 + threadIdx.x;        // < 61440
    int j = idx & 7;
    int lane = (idx >> 3) & 63;
    int frag = idx >> 9;                             // 0..119
    int kq = (lane >> 4) * 8 + j;
    int n15 = lane & 15;
    float v = 0.f;
    if (frag < 60) {                                 // pe_w1: [L][5kt][6nt]
        int l = frag / 30, f = frag % 30;
        int kt = f / 6, nt = f % 6;
        int k = kt * 32 + kq, n = nt * 16 + n15;
        if (k < CAT_DIM && n < EDGE_DIM) v = pe_w1[(l * CAT_DIM + k) * EDGE_DIM + n];
    } else if (frag < 96) {                          // pe_w2: [L][3kt][6nt]
        int f2 = frag - 60; int l = f2 / 18, f = f2 % 18;
        int kt = f / 6, nt = f % 6;
        int k = kt * 32 + kq, n = nt * 16 + n15;
        if (k < EDGE_DIM && n < EDGE_DIM) v = pe_w2[(l * EDGE_DIM + k) * EDGE_DIM + n];
    } else if (frag < 116) {                         // pv_w1: [L][5kt][2nt]
        int f2 = frag - 96; int l = f2 / 10, f = f2 % 10;
        int kt = f / 2, nt = f % 2;
        int k = kt * 32 + kq, n = nt * 16 + n15;
        if (k < CAT_DIM && n < HIDDEN) v = pv_w1[(l * CAT_DIM + k) * HIDDEN + n];
    } else {                                         // pv_w2: [L][1kt][2nt]
        int f2 = frag - 116; int l = f2 / 2, nt = f2 % 2;
        int k = kq, n = nt * 16 + n15;
        if (k < HIDDEN && n < HIDDEN) v = pv_w2[(l * HIDDEN + k) * HIDDEN + n];
    }
    wp[idx] = f2bf(v);
}

// ---------------- node input projection + intrinsic head ----------------
__global__ void k_node_in(const float* __restrict__ x,
                          const float* __restrict__ node_w, const float* __restrict__ node_b,
                          const float* __restrict__ ih_w1, const float* __restrict__ ih_b1,
                          const float* __restrict__ ih_w2, const float* __restrict__ ih_b2,
                          float* __restrict__ h, ushort* __restrict__ h_bf,
                          float* __restrict__ intr) {
    int n = blockIdx.x * blockDim.x + threadIdx.x;
    if (n >= N_NODES) return;
    float xv[NODE_IN];
    const float4* xp = (const float4*)(x + (size_t)n * NODE_IN);
#pragma unroll
    for (int i = 0; i < NODE_IN / 4; i++) {
        float4 v = xp[i];
        xv[4*i+0] = v.x; xv[4*i+1] = v.y; xv[4*i+2] = v.z; xv[4*i+3] = v.w;
    }
    float hv[HIDDEN];
#pragma unroll
    for (int j = 0; j < HIDDEN; j++) hv[j] = node_b[j];
    for (int k = 0; k < NODE_IN; k++) {
        float xk = xv[k];
#pragma unroll
        for (int j = 0; j < HIDDEN; j++) hv[j] = fmaf(xk, node_w[k * HIDDEN + j], hv[j]);
    }
#pragma unroll
    for (int j = 0; j < HIDDEN; j++) {
        h[(size_t)n * HIDDEN + j] = hv[j];
        h_bf[(size_t)n * HIDDEN + j] = f2bf(hv[j]);
    }
    float acc = ih_b2[0];
    for (int j = 0; j < HEAD_HIDDEN; j++) {
        float t = ih_b1[j];
#pragma unroll
        for (int k = 0; k < HIDDEN; k++) t = fmaf(hv[k], ih_w1[k * HEAD_HIDDEN + j], t);
        acc = fmaf(gelu_exact(t), ih_w2[j], acc);
    }
    intr[n] = acc;
}

__global__ void k_counts(const int* __restrict__ ei, int* __restrict__ cnt) {
    int e = blockIdx.x * blockDim.x + threadIdx.x;
    if (e >= N_EDGES) return;
    atomicAdd(&cnt[ei[N_EDGES + e]], 1);
}

// A-fragment gather from global: cat layout [src h 0-23 | dst h 24-47 | e 48-143 | pad].
// Chunks beyond real data are clamped to a safe address; zero-padded weights kill them.
__device__ __forceinline__ short8 ld_catA(const ushort* __restrict__ h_bf,
                                          const float* __restrict__ eattr,
                                          const ushort* __restrict__ e_bf,
                                          int src, int dst, long rowg, int c) {
    if (c < 48) {
        const ushort* p = (c < 24) ? h_bf + (size_t)src * 24 + c
                                   : h_bf + (size_t)dst * 24 + (c - 24);
        return *(const short8*)p;
    }
    int ec = c - 48;
    if (eattr) {
        const float* q = eattr + rowg * 84;
        f32x4 lo = *(const f32x4*)(q + ((ec <= 80) ? ec : 0));
        f32x4 hi = *(const f32x4*)(q + ((ec <= 76) ? (ec + 4) : 0));
        short8 r;
        r[0] = (short)f2bf(lo[0]); r[1] = (short)f2bf(lo[1]);
        r[2] = (short)f2bf(lo[2]); r[3] = (short)f2bf(lo[3]);
        r[4] = (short)f2bf(hi[0]); r[5] = (short)f2bf(hi[1]);
        r[6] = (short)f2bf(hi[2]); r[7] = (short)f2bf(hi[3]);
        return r;
    }
    return *(const short8*)(e_bf + rowg * 96 + ((ec < 96) ? ec : 0));
}

// Same gather but e part comes from LDS (e_new), block-local row.
__device__ __forceinline__ short8 ld_catV(const ushort* __restrict__ h_bf,
                                          const ushort* __restrict__ sT,
                                          int src, int dst, int rowL, int c) {
    if (c < 48) {
        const ushort* p = (c < 24) ? h_bf + (size_t)src * 24 + c
                                   : h_bf + (size_t)dst * 24 + (c - 24);
        return *(const short8*)p;
    }
    int ec = c - 48;
    return *(const short8*)(sT + rowL * 104 + ((ec < 96) ? ec : 0));
}

// ---------------- fused per-layer edge kernel: phi_e + LN + phi_v + scatter ----------------
// 64 edges/block, 4 waves (16 rows each, wave-private) -> 2 barriers total.
// LDS 18944B -> 8 blocks/CU = 32 waves/CU (100%); VGPR cap 64 (no spill: round-0
// code with 2x the accumulators fit 64).
__global__ __launch_bounds__(256, 8)
void k_edge_fused(const ushort* __restrict__ h_bf,
                  const float* __restrict__ eattr,   // layer0 edge_attr fp32, else null
                  ushort* __restrict__ e_bf,         // padded 96-col bf16; in (L>0) / out
                  const int* __restrict__ ei,
                  const ushort* __restrict__ w1f, const ushort* __restrict__ w2f,
                  const ushort* __restrict__ v1f, const ushort* __restrict__ v2f,
                  const float* __restrict__ b1, const float* __restrict__ b2,
                  const float* __restrict__ g, const float* __restrict__ bb,
                  const float* __restrict__ vb1, const float* __restrict__ vb2,
                  float* __restrict__ agg, int store_e) {
    __shared__ __align__(16) ushort sT[64 * 104];    // t1 then e_new, pitch 104
    __shared__ __align__(16) ushort sTV[64 * 40];    // t_v, pitch 40
    __shared__ int s_idx[128];

    const int tid = threadIdx.x;
    const int e0 = blockIdx.x * 64;
    if (tid < 128) s_idx[tid] = ei[(size_t)(tid >> 6) * N_EDGES + e0 + (tid & 63)];
    __syncthreads();

    const int lane = tid & 63, wave = tid >> 6;      // wave 0..3
    const int quad = lane >> 4, l15 = lane & 15;
    const int cbase = quad * 8;
    const int rA = wave * 16 + l15;                  // single A-frag row per wave
    const int srcA = s_idx[rA], dstA = s_idx[64 + rA];

    // ---- GEMM1: t1 = cat @ w1 ----
    f32x4 acc[6];
#pragma unroll
    for (int nt = 0; nt < 6; nt++) acc[nt] = (f32x4)0.f;
#pragma unroll
    for (int kt = 0; kt < 5; kt++) {
        int c = kt * 32 + cbase;
        short8 a = ld_catA(h_bf, eattr, e_bf, srcA, dstA, (long)(e0 + rA), c);
        const short8* bp = (const short8*)w1f + kt * 6 * 64 + lane;
#pragma unroll
        for (int nt = 0; nt < 6; nt++) {
            short8 b = bp[nt * 64];
            acc[nt] = __builtin_amdgcn_mfma_f32_16x16x32_bf16(a, b, acc[nt], 0, 0, 0);
        }
    }
    // gelu -> sT (wave-private rows; pad cols come out exactly 0)
#pragma unroll
    for (int nt = 0; nt < 6; nt++) {
        int col = nt * 16 + l15;
        float bv = (col < EDGE_DIM) ? b1[col] : 0.f;
#pragma unroll
        for (int r = 0; r < 4; r++) {
            int row = wave * 16 + quad * 4 + r;
            sT[row * 104 + col] = f2bf(gelu_exact(acc[nt][r] + bv));
        }
    }

    // ---- GEMM2: t1 @ w2 (rows wave-private, no barrier) ----
    f32x4 acc2[6];
#pragma unroll
    for (int nt = 0; nt < 6; nt++) acc2[nt] = (f32x4)0.f;
#pragma unroll
    for (int kt = 0; kt < 3; kt++) {
        short8 a = *(const short8*)(sT + (size_t)rA * 104 + kt * 32 + cbase);
        const short8* bp = (const short8*)w2f + kt * 6 * 64 + lane;
#pragma unroll
        for (int nt = 0; nt < 6; nt++) {
            short8 b = bp[nt * 64];
            acc2[nt] = __builtin_amdgcn_mfma_f32_16x16x32_bf16(a, b, acc2[nt], 0, 0, 0);
        }
    }

    // ---- bias + residual + LayerNorm -> e_new (bf16) back into sT ----
#pragma unroll
    for (int r = 0; r < 4; r++) {
        int row = wave * 16 + quad * 4 + r;
        long rg = e0 + row;
        float vv[6];
        float ss = 0.f, qq = 0.f;
#pragma unroll
        for (int nt = 0; nt < 6; nt++) {
            int col = nt * 16 + l15;
            float v = 0.f;
            if (col < EDGE_DIM) {
                v = acc2[nt][r] + b2[col];
                v += eattr ? eattr[rg * 84 + col] : bf2f(e_bf[rg * 96 + col]);
            }
            vv[nt] = v; ss += v; qq = fmaf(v, v, qq);
        }
        ss += __shfl_xor(ss, 1); ss += __shfl_xor(ss, 2);
        ss += __shfl_xor(ss, 4); ss += __shfl_xor(ss, 8);
        qq += __shfl_xor(qq, 1); qq += __shfl_xor(qq, 2);
        qq += __shfl_xor(qq, 4); qq += __shfl_xor(qq, 8);
        float mean = ss * (1.f / EDGE_DIM);
        float var  = qq * (1.f / EDGE_DIM) - mean * mean;
        float rstd = rsqrtf(var + LN_EPS);
#pragma unroll
        for (int nt = 0; nt < 6; nt++) {
            int col = nt * 16 + l15;
            if (col < EDGE_DIM)
                sT[row * 104 + col] = f2bf((vv[nt] - mean) * rstd * g[col] + bb[col]);
        }
    }

    // ---- GEMM_V1: [h_src|h_dst|e_new] @ v1 (e from sT, wave-private rows) ----
    f32x4 av[2];
#pragma unroll
    for (int nt = 0; nt < 2; nt++) av[nt] = (f32x4)0.f;
#pragma unroll
    for (int kt = 0; kt < 5; kt++) {
        int c = kt * 32 + cbase;
        short8 a = ld_catV(h_bf, sT, srcA, dstA, rA, c);
        const short8* bp = (const short8*)v1f + kt * 2 * 64 + lane;
#pragma unroll
        for (int nt = 0; nt < 2; nt++) {
            short8 b = bp[nt * 64];
            av[nt] = __builtin_amdgcn_mfma_f32_16x16x32_bf16(a, b, av[nt], 0, 0, 0);
        }
    }
    // gelu -> sTV
#pragma unroll
    for (int nt = 0; nt < 2; nt++) {
        int col = nt * 16 + l15;
        float bv = (col < HIDDEN) ? vb1[col] : 0.f;
#pragma unroll
        for (int r = 0; r < 4; r++) {
            int row = wave * 16 + quad * 4 + r;
            sTV[row * 40 + col] = f2bf(gelu_exact(av[nt][r] + bv));
        }
    }

    // ---- GEMM_V2: t_v @ v2 ----
    f32x4 av2[2];
#pragma unroll
    for (int nt = 0; nt < 2; nt++) av2[nt] = (f32x4)0.f;
    {
        short8 a = *(const short8*)(sTV + (size_t)rA * 40 + cbase);
        const short8* bp = (const short8*)v2f + lane;
#pragma unroll
        for (int nt = 0; nt < 2; nt++) {
            short8 b = bp[nt * 64];
            av2[nt] = __builtin_amdgcn_mfma_f32_16x16x32_bf16(a, b, av2[nt], 0, 0, 0);
        }
    }
    // scatter-add m into agg
#pragma unroll
    for (int nt = 0; nt < 2; nt++) {
        int col = nt * 16 + l15;
        if (col < HIDDEN) {
            float bv = vb2[col];
#pragma unroll
            for (int r = 0; r < 4; r++) {
                int row = wave * 16 + quad * 4 + r;
                int d = s_idx[64 + row];
                atomicAdd(&agg[(size_t)d * HIDDEN + col], av2[nt][r] + bv);
            }
        }
    }

    // ---- store e_new (padded 96-col bf16), skipped on last layer ----
    if (store_e) {
        __syncthreads();
        const uint* sTu = (const uint*)sT;           // pitch 52 dwords
        uint* dst32 = (uint*)e_bf + (size_t)e0 * 48;
#pragma unroll
        for (int i = 0; i < 12; i++) {
            int idx = tid + 256 * i;                 // < 3072
            int row = idx / 48, d = idx - row * 48;
            dst32[idx] = sTu[row * 52 + d];
        }
    }
}

// ---------------- node update: h = LN(h + agg/counts) ----------------
__global__ void k_node_up(float* __restrict__ h, ushort* __restrict__ h_bf,
                          const float* __restrict__ agg,
                          const int* __restrict__ cnt,
                          const float* __restrict__ g, const float* __restrict__ b) {
    int n = blockIdx.x * blockDim.x + threadIdx.x;
    if (n >= N_NODES) return;
    int c = cnt[n]; if (c < 1) c = 1;
    float inv = 1.0f / (float)c;
    float v[HIDDEN];
    float s = 0.f;
#pragma unroll
    for (int j = 0; j < HIDDEN; j++) {
        v[j] = h[(size_t)n * HIDDEN + j] + agg[(size_t)n * HIDDEN + j] * inv;
        s += v[j];
    }
    float mean = s * (1.f / HIDDEN);
    float sq = 0.f;
#pragma unroll
    for (int j = 0; j < HIDDEN; j++) { float d = v[j] - mean; sq = fmaf(d, d, sq); }
    float rstd = rsqrtf(sq * (1.f / HIDDEN) + LN_EPS);
#pragma unroll
    for (int j = 0; j < HIDDEN; j++) {
        float o = (v[j] - mean) * rstd * g[j] + b[j];
        h[(size_t)n * HIDDEN + j] = o;
        h_bf[(size_t)n * HIDDEN + j] = f2bf(o);
    }
}

// ---------------- final: out = mu + intrinsic + context(h) ----------------
__global__ void k_final(const float* __restrict__ h, const float* __restrict__ intr,
                        const float* __restrict__ ch_w1, const float* __restrict__ ch_b1,
                        const float* __restrict__ ch_w2, const float* __restrict__ ch_b2,
                        const float* __restrict__ mu, float* __restrict__ out) {
    int n = blockIdx.x * blockDim.x + threadIdx.x;
    if (n >= N_NODES) return;
    float hv[HIDDEN];
#pragma unroll
    for (int j = 0; j < HIDDEN; j++) hv[j] = h[(size_t)n * HIDDEN + j];
    float acc = ch_b2[0];
    for (int j = 0; j < HEAD_HIDDEN; j++) {
        float t = ch_b1[j];
#pragma unroll
        for (int k = 0; k < HIDDEN; k++) t = fmaf(hv[k], ch_w1[k * HEAD_HIDDEN + j], t);
        acc = fmaf(gelu_exact(t), ch_w2[j], acc);
    }
    out[n] = mu[0] + intr[n] + acc;
}

extern "C" void kernel_launch(void* const* d_in, const int* in_sizes, int n_in,
                              void* d_out, int out_size, void* d_ws, size_t ws_size,
                              hipStream_t stream) {
    const float* x        = (const float*)d_in[0];
    const float* edge_attr= (const float*)d_in[1];
    const float* node_w   = (const float*)d_in[2];
    const float* node_b   = (const float*)d_in[3];
    const float* ih_w1    = (const float*)d_in[4];
    const float* ih_b1    = (const float*)d_in[5];
    const float* ih_w2    = (const float*)d_in[6];
    const float* ih_b2    = (const float*)d_in[7];
    const float* pe_w1    = (const float*)d_in[8];
    const float* pe_b1    = (const float*)d_in[9];
    const float* pe_w2    = (const float*)d_in[10];
    const float* pe_b2    = (const float*)d_in[11];
    const float* pv_w1    = (const float*)d_in[12];
    const float* pv_b1    = (const float*)d_in[13];
    const float* pv_w2    = (const float*)d_in[14];
    const float* pv_b2    = (const float*)d_in[15];
    const float* ne_g     = (const float*)d_in[16];
    const float* ne_b     = (const float*)d_in[17];
    const float* nv_g     = (const float*)d_in[18];
    const float* nv_b     = (const float*)d_in[19];
    const float* ch_w1    = (const float*)d_in[20];
    const float* ch_b1    = (const float*)d_in[21];
    const float* ch_w2    = (const float*)d_in[22];
    const float* ch_b2    = (const float*)d_in[23];
    const float* mu       = (const float*)d_in[24];
    const int*   ei       = (const int*)d_in[25];

    char* ws = (char*)d_ws;
    float*  h    = (float*)ws;  ws += (size_t)N_NODES * HIDDEN * 4;
    float*  agg  = (float*)ws;  ws += (size_t)N_NODES * HIDDEN * 4;
    float*  intr = (float*)ws;  ws += (size_t)N_NODES * 4;
    int*    cnt  = (int*)ws;    ws += (size_t)N_NODES * 4;
    ushort* h_bf = (ushort*)ws; ws += (size_t)N_NODES * HIDDEN * 2;
    ushort* wp   = (ushort*)ws; ws += (size_t)61440 * 2;
    ws = (char*)(((size_t)ws + 255) & ~(size_t)255);
    ushort* e_bf = (ushort*)ws; ws += (size_t)N_EDGES * 96 * 2;   // padded 96 cols

    const ushort* we1[2] = { wp + 0 * 15360, wp + 1 * 15360 };
    const ushort* we2[2] = { wp + 30720 + 0 * 9216, wp + 30720 + 1 * 9216 };
    const ushort* wv1[2] = { wp + 49152 + 0 * 5120, wp + 49152 + 1 * 5120 };
    const ushort* wv2[2] = { wp + 59392 + 0 * 1024, wp + 59392 + 1 * 1024 };

    hipMemsetAsync(cnt, 0, (size_t)N_NODES * 4, stream);
    k_prep_w<<<240, 256, 0, stream>>>(pe_w1, pe_w2, pv_w1, pv_w2, wp);
    k_counts<<<(N_EDGES + 255) / 256, 256, 0, stream>>>(ei, cnt);
    k_node_in<<<(N_NODES + 255) / 256, 256, 0, stream>>>(
        x, node_w, node_b, ih_w1, ih_b1, ih_w2, ih_b2, h, h_bf, intr);

    const int eb = N_EDGES / 64;    // 12500, exact
    for (int L = 0; L < 2; L++) {
        hipMemsetAsync(agg, 0, (size_t)N_NODES * HIDDEN * 4, stream);
        k_edge_fused<<<eb, 256, 0, stream>>>(
            h_bf, (L == 0) ? edge_attr : (const float*)nullptr, e_bf, ei,
            we1[L], we2[L], wv1[L], wv2[L],
            pe_b1 + (size_t)L * EDGE_DIM, pe_b2 + (size_t)L * EDGE_DIM,
            ne_g + (size_t)L * EDGE_DIM, ne_b + (size_t)L * EDGE_DIM,
            pv_b1 + (size_t)L * HIDDEN, pv_b2 + (size_t)L * HIDDEN,
            agg, (L == 0) ? 1 : 0);
        k_node_up<<<(N_NODES + 255) / 256, 256, 0, stream>>>(
            h, h_bf, agg, cnt, nv_g + (size_t)L * HIDDEN, nv_b + (size_t)L * HIDDEN);
    }
    k_final<<<(N_NODES + 255) / 256, 256, 0, stream>>>(
        h, intr, ch_w1, ch_b1, ch_w2, ch_b2, mu, (float*)d_out);
}

// Round 4
// 1052.413 us; speedup vs baseline: 1.2116x; 1.0807x over previous
//
#include <hip/hip_runtime.h>
#include <math.h>

#define N_NODES 100000
#define N_EDGES 800000
#define NODE_IN 32
#define EDGE_DIM 84
#define HIDDEN 24
#define HEAD_HIDDEN 20
#define CAT_DIM 132
#define LN_EPS 1e-5f

typedef __attribute__((ext_vector_type(8))) short short8;
typedef __attribute__((ext_vector_type(4))) short bfx4;
typedef __attribute__((ext_vector_type(4))) float f32x4;
typedef unsigned int uint;
typedef unsigned short ushort;

__device__ __forceinline__ float gelu_exact(float x) {
    return 0.5f * x * (1.0f + erff(x * 0.70710678118654752f));
}
__device__ __forceinline__ ushort f2bf(float f) {
    union { float f; uint u; } c; c.f = f;
    uint u = c.u;
    return (ushort)((u + 0x7fffu + ((u >> 16) & 1u)) >> 16);
}
__device__ __forceinline__ float bf2f(ushort s) {
    union { uint u; float f; } c; c.u = ((uint)s) << 16; return c.f;
}

// ---------------- weight pre-pack to MFMA-fragment-major bf16 ----------------
// frag element (lane, j) = W[kt*32 + (lane>>4)*8 + j][nt*16 + (lane&15)], zero-padded.
// regions (frags of 512 bf16): pe_w1 2L*30 | pe_w2 2L*18 | pv_w1 2L*10 | pv_w2 2L*2
__global__ void k_prep_w(const float* __restrict__ pe_w1, const float* __restrict__ pe_w2,
                         const float* __restrict__ pv_w1, const float* __restrict__ pv_w2,
                         ushort* __restrict__ wp) {
    int idx = blockIdx.x * 256 + threadIdx.x;        // < 61440
    int j = idx & 7;
    int lane = (idx >> 3) & 63;
    int frag = idx >> 9;                             // 0..119
    int kq = (lane >> 4) * 8 + j;
    int n15 = lane & 15;
    float v = 0.f;
    if (frag < 60) {                                 // pe_w1: [L][5kt][6nt]
        int l = frag / 30, f = frag % 30;
        int kt = f / 6, nt = f % 6;
        int k = kt * 32 + kq, n = nt * 16 + n15;
        if (k < CAT_DIM && n < EDGE_DIM) v = pe_w1[(l * CAT_DIM + k) * EDGE_DIM + n];
    } else if (frag < 96) {                          // pe_w2: [L][3kt][6nt]
        int f2 = frag - 60; int l = f2 / 18, f = f2 % 18;
        int kt = f / 6, nt = f % 6;
        int k = kt * 32 + kq, n = nt * 16 + n15;
        if (k < EDGE_DIM && n < EDGE_DIM) v = pe_w2[(l * EDGE_DIM + k) * EDGE_DIM + n];
    } else if (frag < 116) {                         // pv_w1: [L][5kt][2nt]
        int f2 = frag - 96; int l = f2 / 10, f = f2 % 10;
        int kt = f / 2, nt = f % 2;
        int k = kt * 32 + kq, n = nt * 16 + n15;
        if (k < CAT_DIM && n < HIDDEN) v = pv_w1[(l * CAT_DIM + k) * HIDDEN + n];
    } else {                                         // pv_w2: [L][1kt][2nt]
        int f2 = frag - 116; int l = f2 / 2, nt = f2 % 2;
        int k = kq, n = nt * 16 + n15;
        if (k < HIDDEN && n < HIDDEN) v = pv_w2[(l * HIDDEN + k) * HIDDEN + n];
    }
    wp[idx] = f2bf(v);
}

// ---------------- node input projection + intrinsic head ----------------
__global__ void k_node_in(const float* __restrict__ x,
                          const float* __restrict__ node_w, const float* __restrict__ node_b,
                          const float* __restrict__ ih_w1, const float* __restrict__ ih_b1,
                          const float* __restrict__ ih_w2, const float* __restrict__ ih_b2,
                          float* __restrict__ h, ushort* __restrict__ h_bf,
                          float* __restrict__ intr) {
    int n = blockIdx.x * blockDim.x + threadIdx.x;
    if (n >= N_NODES) return;
    float xv[NODE_IN];
    const float4* xp = (const float4*)(x + (size_t)n * NODE_IN);
#pragma unroll
    for (int i = 0; i < NODE_IN / 4; i++) {
        float4 v = xp[i];
        xv[4*i+0] = v.x; xv[4*i+1] = v.y; xv[4*i+2] = v.z; xv[4*i+3] = v.w;
    }
    float hv[HIDDEN];
#pragma unroll
    for (int j = 0; j < HIDDEN; j++) hv[j] = node_b[j];
    for (int k = 0; k < NODE_IN; k++) {
        float xk = xv[k];
#pragma unroll
        for (int j = 0; j < HIDDEN; j++) hv[j] = fmaf(xk, node_w[k * HIDDEN + j], hv[j]);
    }
#pragma unroll
    for (int j = 0; j < HIDDEN; j++) {
        h[(size_t)n * HIDDEN + j] = hv[j];
        h_bf[(size_t)n * HIDDEN + j] = f2bf(hv[j]);
    }
    float acc = ih_b2[0];
    for (int j = 0; j < HEAD_HIDDEN; j++) {
        float t = ih_b1[j];
#pragma unroll
        for (int k = 0; k < HIDDEN; k++) t = fmaf(hv[k], ih_w1[k * HEAD_HIDDEN + j], t);
        acc = fmaf(gelu_exact(t), ih_w2[j], acc);
    }
    intr[n] = acc;
}

__global__ void k_counts(const int* __restrict__ ei, int* __restrict__ cnt) {
    int e = blockIdx.x * blockDim.x + threadIdx.x;
    if (e >= N_EDGES) return;
    atomicAdd(&cnt[ei[N_EDGES + e]], 1);
}

// ---------------- fused per-layer edge kernel: phi_e + LN + phi_v + scatter ----------------
// 64 edges/block, 4 waves x 16 wave-private rows. Whole cat tile staged in LDS once
// (1 barrier total). LDS 23040B -> 7 blocks/CU = 28 waves (87.5%).
// Register budget: no gather math inside MFMA loops -> fits 64 VGPR+AGPR (8 waves/EU).
// sCat row layout (bf16, pitch 136): [hs 0-23 | hd 24-47 | e/t1/e_new 48-135].
// All out-of-range A-frag reads are clamped in-bounds and hit zero-padded weights.
__global__ __launch_bounds__(256, 8)
void k_edge_fused(const ushort* __restrict__ h_bf,
                  const float* __restrict__ eattr,   // layer0 edge_attr fp32, else null
                  ushort* __restrict__ e_bf,         // padded 88-col bf16; in (L>0) / out
                  const int* __restrict__ ei,
                  const ushort* __restrict__ w1f, const ushort* __restrict__ w2f,
                  const ushort* __restrict__ v1f, const ushort* __restrict__ v2f,
                  const float* __restrict__ b1, const float* __restrict__ b2,
                  const float* __restrict__ g, const float* __restrict__ bb,
                  const float* __restrict__ vb1, const float* __restrict__ vb2,
                  float* __restrict__ agg, int store_e) {
    __shared__ __align__(16) ushort sCat[64 * 136]; // 17408 B
    __shared__ __align__(16) ushort sTV[64 * 40];   // 5120 B
    __shared__ int s_idx[128];

    const int tid = threadIdx.x;
    const int e0 = blockIdx.x * 64;

    // ---- staging: s_idx + h gather + e convert, then ONE barrier ----
    if (tid < 128) s_idx[tid] = ei[(size_t)(tid >> 6) * N_EDGES + e0 + (tid & 63)];
#pragma unroll
    for (int i = 0; i < 2; i++) {
        int idx = tid + 256 * i;                     // < 384 = 64 rows * 6 chunks
        if (idx < 384) {
            int row = idx / 6, part = idx - row * 6; // part 0-2: src, 3-5: dst
            int node = ei[(size_t)(part >= 3) * N_EDGES + e0 + row];
            short8 v = *(const short8*)(h_bf + (size_t)node * 24 + (part % 3) * 8);
            *(short8*)(sCat + row * 136 + part * 8) = v;
        }
    }
    if (eattr) {
#pragma unroll
        for (int i = 0; i < 6; i++) {
            int u = tid + 256 * i;                   // < 1344 = 64 rows * 21 f32x4
            if (u < 1344) {
                int row = u / 21, c4 = u - row * 21;
                f32x4 v = *(const f32x4*)(eattr + (size_t)(e0 + row) * 84 + c4 * 4);
                bfx4 w;
                w[0] = (short)f2bf(v[0]); w[1] = (short)f2bf(v[1]);
                w[2] = (short)f2bf(v[2]); w[3] = (short)f2bf(v[3]);
                *(bfx4*)(sCat + row * 136 + 48 + c4 * 4) = w;
            }
        }
        // zero pad cols 132-135 (64 rows * 4 = 256)
        sCat[(tid >> 2) * 136 + 132 + (tid & 3)] = 0;
    } else {
#pragma unroll
        for (int i = 0; i < 3; i++) {
            int u = tid + 256 * i;                   // < 704 = 64 rows * 11 short8
            if (u < 704) {
                int row = u / 11, c8 = u - row * 11; // e_bf cols 84-87 are zeros -> pad ok
                *(short8*)(sCat + row * 136 + 48 + c8 * 8) =
                    *(const short8*)(e_bf + (size_t)(e0 + row) * 88 + c8 * 8);
            }
        }
    }
    __syncthreads();                                 // the only barrier

    const int lane = tid & 63, wave = tid >> 6;      // wave 0..3
    const int quad = lane >> 4, l15 = lane & 15;
    const int cbase = quad * 8;
    const int rA = wave * 16 + l15;                  // A-frag row (wave-private)

    // ---- GEMM1: t1 = cat @ w1 (A from LDS) ----
    f32x4 acc[6];
#pragma unroll
    for (int nt = 0; nt < 6; nt++) acc[nt] = (f32x4)0.f;
#pragma unroll
    for (int kt = 0; kt < 5; kt++) {
        int c = kt * 32 + cbase; if (c > 128) c = 128;   // clamped reads hit zero weights
        short8 a = *(const short8*)(sCat + rA * 136 + c);
        const short8* bp = (const short8*)w1f + kt * 6 * 64 + lane;
#pragma unroll
        for (int nt = 0; nt < 6; nt++) {
            short8 b = bp[nt * 64];
            acc[nt] = __builtin_amdgcn_mfma_f32_16x16x32_bf16(a, b, acc[nt], 0, 0, 0);
        }
    }
    // gelu -> t1 over sCat e-region (cols 48-135, wave-private rows; pads exact 0)
#pragma unroll
    for (int nt = 0; nt < 6; nt++) {
        int col = nt * 16 + l15;
        float bv = (col < EDGE_DIM) ? b1[col] : 0.f;
#pragma unroll
        for (int r = 0; r < 4; r++) {
            int row = wave * 16 + quad * 4 + r;
            if (col < 88) sCat[row * 136 + 48 + col] = f2bf(gelu_exact(acc[nt][r] + bv));
        }
    }

    // ---- GEMM2: t1 @ w2 (wave-private, no barrier) ----
    f32x4 acc2[6];
#pragma unroll
    for (int nt = 0; nt < 6; nt++) acc2[nt] = (f32x4)0.f;
#pragma unroll
    for (int kt = 0; kt < 3; kt++) {
        int c = kt * 32 + cbase; if (c > 80) c = 80;
        short8 a = *(const short8*)(sCat + rA * 136 + 48 + c);
        const short8* bp = (const short8*)w2f + kt * 6 * 64 + lane;
#pragma unroll
        for (int nt = 0; nt < 6; nt++) {
            short8 b = bp[nt * 64];
            acc2[nt] = __builtin_amdgcn_mfma_f32_16x16x32_bf16(a, b, acc2[nt], 0, 0, 0);
        }
    }

    // ---- bias + residual + LayerNorm -> e_new back over sCat cols 48-131 ----
#pragma unroll
    for (int r = 0; r < 4; r++) {
        int row = wave * 16 + quad * 4 + r;
        long rg = e0 + row;
        float vv[6];
        float ss = 0.f, qq = 0.f;
#pragma unroll
        for (int nt = 0; nt < 6; nt++) {
            int col = nt * 16 + l15;
            float v = 0.f;
            if (col < EDGE_DIM) {
                v = acc2[nt][r] + b2[col];
                v += eattr ? eattr[rg * 84 + col] : bf2f(e_bf[rg * 88 + col]);
            }
            vv[nt] = v; ss += v; qq = fmaf(v, v, qq);
        }
        ss += __shfl_xor(ss, 1); ss += __shfl_xor(ss, 2);
        ss += __shfl_xor(ss, 4); ss += __shfl_xor(ss, 8);
        qq += __shfl_xor(qq, 1); qq += __shfl_xor(qq, 2);
        qq += __shfl_xor(qq, 4); qq += __shfl_xor(qq, 8);
        float mean = ss * (1.f / EDGE_DIM);
        float var  = qq * (1.f / EDGE_DIM) - mean * mean;
        float rstd = rsqrtf(var + LN_EPS);
#pragma unroll
        for (int nt = 0; nt < 6; nt++) {
            int col = nt * 16 + l15;
            if (col < EDGE_DIM)
                sCat[row * 136 + 48 + col] = f2bf((vv[nt] - mean) * rstd * g[col] + bb[col]);
        }
    }

    // ---- GEMM_V1: [hs|hd|e_new] @ v1 (full cat row from LDS again) ----
    f32x4 av[2];
#pragma unroll
    for (int nt = 0; nt < 2; nt++) av[nt] = (f32x4)0.f;
#pragma unroll
    for (int kt = 0; kt < 5; kt++) {
        int c = kt * 32 + cbase; if (c > 128) c = 128;
        short8 a = *(const short8*)(sCat + rA * 136 + c);
        const short8* bp = (const short8*)v1f + kt * 2 * 64 + lane;
#pragma unroll
        for (int nt = 0; nt < 2; nt++) {
            short8 b = bp[nt * 64];
            av[nt] = __builtin_amdgcn_mfma_f32_16x16x32_bf16(a, b, av[nt], 0, 0, 0);
        }
    }
    // gelu -> sTV
#pragma unroll
    for (int nt = 0; nt < 2; nt++) {
        int col = nt * 16 + l15;
        float bv = (col < HIDDEN) ? vb1[col] : 0.f;
#pragma unroll
        for (int r = 0; r < 4; r++) {
            int row = wave * 16 + quad * 4 + r;
            sTV[row * 40 + col] = f2bf(gelu_exact(av[nt][r] + bv));
        }
    }

    // ---- GEMM_V2: t_v @ v2 ----
    f32x4 av2[2];
#pragma unroll
    for (int nt = 0; nt < 2; nt++) av2[nt] = (f32x4)0.f;
    {
        short8 a = *(const short8*)(sTV + (size_t)rA * 40 + cbase);
        const short8* bp = (const short8*)v2f + lane;
#pragma unroll
        for (int nt = 0; nt < 2; nt++) {
            short8 b = bp[nt * 64];
            av2[nt] = __builtin_amdgcn_mfma_f32_16x16x32_bf16(a, b, av2[nt], 0, 0, 0);
        }
    }
    // scatter-add m into agg
#pragma unroll
    for (int nt = 0; nt < 2; nt++) {
        int col = nt * 16 + l15;
        if (col < HIDDEN) {
            float bv = vb2[col];
#pragma unroll
            for (int r = 0; r < 4; r++) {
                int row = wave * 16 + quad * 4 + r;
                int d = s_idx[64 + row];
                atomicAdd(&agg[(size_t)d * HIDDEN + col], av2[nt][r] + bv);
            }
        }
    }

    // ---- store e_new (88-col bf16), wave-private rows, no barrier ----
    if (store_e) {
        const uint* sU = (const uint*)sCat;          // pitch 68 dwords
        uint* dst32 = (uint*)e_bf;                   // pitch 44 dwords
#pragma unroll
        for (int i = 0; i < 11; i++) {
            int idx = lane + 64 * i;                 // < 704 = 16 rows * 44 dwords
            int rl = idx / 44, d = idx - rl * 44;
            int row = wave * 16 + rl;
            dst32[(size_t)(e0 + row) * 44 + d] = sU[row * 68 + 24 + d];
        }
    }
}

// ---------------- node update: h = LN(h + agg/counts) ----------------
__global__ void k_node_up(float* __restrict__ h, ushort* __restrict__ h_bf,
                          const float* __restrict__ agg,
                          const int* __restrict__ cnt,
                          const float* __restrict__ g, const float* __restrict__ b) {
    int n = blockIdx.x * blockDim.x + threadIdx.x;
    if (n >= N_NODES) return;
    int c = cnt[n]; if (c < 1) c = 1;
    float inv = 1.0f / (float)c;
    float v[HIDDEN];
    float s = 0.f;
#pragma unroll
    for (int j = 0; j < HIDDEN; j++) {
        v[j] = h[(size_t)n * HIDDEN + j] + agg[(size_t)n * HIDDEN + j] * inv;
        s += v[j];
    }
    float mean = s * (1.f / HIDDEN);
    float sq = 0.f;
#pragma unroll
    for (int j = 0; j < HIDDEN; j++) { float d = v[j] - mean; sq = fmaf(d, d, sq); }
    float rstd = rsqrtf(sq * (1.f / HIDDEN) + LN_EPS);
#pragma unroll
    for (int j = 0; j < HIDDEN; j++) {
        float o = (v[j] - mean) * rstd * g[j] + b[j];
        h[(size_t)n * HIDDEN + j] = o;
        h_bf[(size_t)n * HIDDEN + j] = f2bf(o);
    }
}

// ---------------- final: out = mu + intrinsic + context(h) ----------------
__global__ void k_final(const float* __restrict__ h, const float* __restrict__ intr,
                        const float* __restrict__ ch_w1, const float* __restrict__ ch_b1,
                        const float* __restrict__ ch_w2, const float* __restrict__ ch_b2,
                        const float* __restrict__ mu, float* __restrict__ out) {
    int n = blockIdx.x * blockDim.x + threadIdx.x;
    if (n >= N_NODES) return;
    float hv[HIDDEN];
#pragma unroll
    for (int j = 0; j < HIDDEN; j++) hv[j] = h[(size_t)n * HIDDEN + j];
    float acc = ch_b2[0];
    for (int j = 0; j < HEAD_HIDDEN; j++) {
        float t = ch_b1[j];
#pragma unroll
        for (int k = 0; k < HIDDEN; k++) t = fmaf(hv[k], ch_w1[k * HEAD_HIDDEN + j], t);
        acc = fmaf(gelu_exact(t), ch_w2[j], acc);
    }
    out[n] = mu[0] + intr[n] + acc;
}

extern "C" void kernel_launch(void* const* d_in, const int* in_sizes, int n_in,
                              void* d_out, int out_size, void* d_ws, size_t ws_size,
                              hipStream_t stream) {
    const float* x        = (const float*)d_in[0];
    const float* edge_attr= (const float*)d_in[1];
    const float* node_w   = (const float*)d_in[2];
    const float* node_b   = (const float*)d_in[3];
    const float* ih_w1    = (const float*)d_in[4];
    const float* ih_b1    = (const float*)d_in[5];
    const float* ih_w2    = (const float*)d_in[6];
    const float* ih_b2    = (const float*)d_in[7];
    const float* pe_w1    = (const float*)d_in[8];
    const float* pe_b1    = (const float*)d_in[9];
    const float* pe_w2    = (const float*)d_in[10];
    const float* pe_b2    = (const float*)d_in[11];
    const float* pv_w1    = (const float*)d_in[12];
    const float* pv_b1    = (const float*)d_in[13];
    const float* pv_w2    = (const float*)d_in[14];
    const float* pv_b2    = (const float*)d_in[15];
    const float* ne_g     = (const float*)d_in[16];
    const float* ne_b     = (const float*)d_in[17];
    const float* nv_g     = (const float*)d_in[18];
    const float* nv_b     = (const float*)d_in[19];
    const float* ch_w1    = (const float*)d_in[20];
    const float* ch_b1    = (const float*)d_in[21];
    const float* ch_w2    = (const float*)d_in[22];
    const float* ch_b2    = (const float*)d_in[23];
    const float* mu       = (const float*)d_in[24];
    const int*   ei       = (const int*)d_in[25];

    char* ws = (char*)d_ws;
    float*  h    = (float*)ws;  ws += (size_t)N_NODES * HIDDEN * 4;
    float*  agg  = (float*)ws;  ws += (size_t)N_NODES * HIDDEN * 4;
    float*  intr = (float*)ws;  ws += (size_t)N_NODES * 4;
    int*    cnt  = (int*)ws;    ws += (size_t)N_NODES * 4;
    ushort* h_bf = (ushort*)ws; ws += (size_t)N_NODES * HIDDEN * 2;
    ushort* wp   = (ushort*)ws; ws += (size_t)61440 * 2;
    ws = (char*)(((size_t)ws + 255) & ~(size_t)255);
    ushort* e_bf = (ushort*)ws; ws += (size_t)N_EDGES * 88 * 2;   // padded 88 cols

    const ushort* we1[2] = { wp + 0 * 15360, wp + 1 * 15360 };
    const ushort* we2[2] = { wp + 30720 + 0 * 9216, wp + 30720 + 1 * 9216 };
    const ushort* wv1[2] = { wp + 49152 + 0 * 5120, wp + 49152 + 1 * 5120 };
    const ushort* wv2[2] = { wp + 59392 + 0 * 1024, wp + 59392 + 1 * 1024 };

    hipMemsetAsync(cnt, 0, (size_t)N_NODES * 4, stream);
    k_prep_w<<<240, 256, 0, stream>>>(pe_w1, pe_w2, pv_w1, pv_w2, wp);
    k_counts<<<(N_EDGES + 255) / 256, 256, 0, stream>>>(ei, cnt);
    k_node_in<<<(N_NODES + 255) / 256, 256, 0, stream>>>(
        x, node_w, node_b, ih_w1, ih_b1, ih_w2, ih_b2, h, h_bf, intr);

    const int eb = N_EDGES / 64;    // 12500, exact
    for (int L = 0; L < 2; L++) {
        hipMemsetAsync(agg, 0, (size_t)N_NODES * HIDDEN * 4, stream);
        k_edge_fused<<<eb, 256, 0, stream>>>(
            h_bf, (L == 0) ? edge_attr : (const float*)nullptr, e_bf, ei,
            we1[L], we2[L], wv1[L], wv2[L],
            pe_b1 + (size_t)L * EDGE_DIM, pe_b2 + (size_t)L * EDGE_DIM,
            ne_g + (size_t)L * EDGE_DIM, ne_b + (size_t)L * EDGE_DIM,
            pv_b1 + (size_t)L * HIDDEN, pv_b2 + (size_t)L * HIDDEN,
            agg, (L == 0) ? 1 : 0);
        k_node_up<<<(N_NODES + 255) / 256, 256, 0, stream>>>(
            h, h_bf, agg, cnt, nv_g + (size_t)L * HIDDEN, nv_b + (size_t)L * HIDDEN);
    }
    k_final<<<(N_NODES + 255) / 256, 256, 0, stream>>>(
        h, intr, ch_w1, ch_b1, ch_w2, ch_b2, mu, (float*)d_out);
}

// Round 5
// 943.086 us; speedup vs baseline: 1.3521x; 1.1159x over previous
//
#include <hip/hip_runtime.h>
#include <math.h>

#define N_NODES 100000
#define N_EDGES 800000
#define NODE_IN 32
#define EDGE_DIM 84
#define HIDDEN 24
#define HEAD_HIDDEN 20
#define CAT_DIM 132
#define LN_EPS 1e-5f

typedef __attribute__((ext_vector_type(8))) short short8;
typedef __attribute__((ext_vector_type(4))) short bfx4;
typedef __attribute__((ext_vector_type(4))) float f32x4;
typedef unsigned int uint;
typedef unsigned short ushort;

__device__ __forceinline__ float gelu_exact(float x) {
    return 0.5f * x * (1.0f + erff(x * 0.70710678118654752f));
}
__device__ __forceinline__ ushort f2bf(float f) {
    union { float f; uint u; } c; c.f = f;
    uint u = c.u;
    return (ushort)((u + 0x7fffu + ((u >> 16) & 1u)) >> 16);
}
__device__ __forceinline__ float bf2f(ushort s) {
    union { uint u; float f; } c; c.u = ((uint)s) << 16; return c.f;
}

// ---------------- weight pre-pack to MFMA-fragment-major bf16 ----------------
// frag element (lane, j) = W[kt*32 + (lane>>4)*8 + j][nt*16 + (lane&15)], zero-padded.
// regions (frags of 512 bf16): pe_w1 2L*30 | pe_w2 2L*18 | pv_w1 2L*10 | pv_w2 2L*2
__global__ void k_prep_w(const float* __restrict__ pe_w1, const float* __restrict__ pe_w2,
                         const float* __restrict__ pv_w1, const float* __restrict__ pv_w2,
                         ushort* __restrict__ wp) {
    int idx = blockIdx.x * 256 + threadIdx.x;        // < 61440
    int j = idx & 7;
    int lane = (idx >> 3) & 63;
    int frag = idx >> 9;                             // 0..119
    int kq = (lane >> 4) * 8 + j;
    int n15 = lane & 15;
    float v = 0.f;
    if (frag < 60) {                                 // pe_w1: [L][5kt][6nt]
        int l = frag / 30, f = frag % 30;
        int kt = f / 6, nt = f % 6;
        int k = kt * 32 + kq, n = nt * 16 + n15;
        if (k < CAT_DIM && n < EDGE_DIM) v = pe_w1[(l * CAT_DIM + k) * EDGE_DIM + n];
    } else if (frag < 96) {                          // pe_w2: [L][3kt][6nt]
        int f2 = frag - 60; int l = f2 / 18, f = f2 % 18;
        int kt = f / 6, nt = f % 6;
        int k = kt * 32 + kq, n = nt * 16 + n15;
        if (k < EDGE_DIM && n < EDGE_DIM) v = pe_w2[(l * EDGE_DIM + k) * EDGE_DIM + n];
    } else if (frag < 116) {                         // pv_w1: [L][5kt][2nt]
        int f2 = frag - 96; int l = f2 / 10, f = f2 % 10;
        int kt = f / 2, nt = f % 2;
        int k = kt * 32 + kq, n = nt * 16 + n15;
        if (k < CAT_DIM && n < HIDDEN) v = pv_w1[(l * CAT_DIM + k) * HIDDEN + n];
    } else {                                         // pv_w2: [L][1kt][2nt]
        int f2 = frag - 116; int l = f2 / 2, nt = f2 % 2;
        int k = kq, n = nt * 16 + n15;
        if (k < HIDDEN && n < HIDDEN) v = pv_w2[(l * HIDDEN + k) * HIDDEN + n];
    }
    wp[idx] = f2bf(v);
}

// ---------------- node input projection + intrinsic head ----------------
__global__ void k_node_in(const float* __restrict__ x,
                          const float* __restrict__ node_w, const float* __restrict__ node_b,
                          const float* __restrict__ ih_w1, const float* __restrict__ ih_b1,
                          const float* __restrict__ ih_w2, const float* __restrict__ ih_b2,
                          float* __restrict__ h, ushort* __restrict__ h_bf,
                          float* __restrict__ intr) {
    int n = blockIdx.x * blockDim.x + threadIdx.x;
    if (n >= N_NODES) return;
    float xv[NODE_IN];
    const float4* xp = (const float4*)(x + (size_t)n * NODE_IN);
#pragma unroll
    for (int i = 0; i < NODE_IN / 4; i++) {
        float4 v = xp[i];
        xv[4*i+0] = v.x; xv[4*i+1] = v.y; xv[4*i+2] = v.z; xv[4*i+3] = v.w;
    }
    float hv[HIDDEN];
#pragma unroll
    for (int j = 0; j < HIDDEN; j++) hv[j] = node_b[j];
    for (int k = 0; k < NODE_IN; k++) {
        float xk = xv[k];
#pragma unroll
        for (int j = 0; j < HIDDEN; j++) hv[j] = fmaf(xk, node_w[k * HIDDEN + j], hv[j]);
    }
#pragma unroll
    for (int j = 0; j < HIDDEN; j++) {
        h[(size_t)n * HIDDEN + j] = hv[j];
        h_bf[(size_t)n * HIDDEN + j] = f2bf(hv[j]);
    }
    float acc = ih_b2[0];
    for (int j = 0; j < HEAD_HIDDEN; j++) {
        float t = ih_b1[j];
#pragma unroll
        for (int k = 0; k < HIDDEN; k++) t = fmaf(hv[k], ih_w1[k * HEAD_HIDDEN + j], t);
        acc = fmaf(gelu_exact(t), ih_w2[j], acc);
    }
    intr[n] = acc;
}

__global__ void k_counts(const int* __restrict__ ei, int* __restrict__ cnt) {
    int e = blockIdx.x * blockDim.x + threadIdx.x;
    if (e >= N_EDGES) return;
    atomicAdd(&cnt[ei[N_EDGES + e]], 1);
}

// ---------------- fused per-layer edge kernel: phi_e + LN + phi_v + scatter ----------------
// 64 edges/block, 4 waves x 16 wave-private rows, cat tile staged in LDS (1 barrier).
// LDS 17920B (t_v reuses dead hs/hd cols after GEMM_V1). Register diet:
// GEMM1 split into two 3-nt passes (12 acc regs), min-waves 7 -> budget 72 regs.
// sCat row layout (bf16, pitch 136): [hs 0-23 | hd 24-47 | e/t1/e_new 48-135];
// t_v overwrites cols 0-31 after V1. All clamped reads hit zero-padded weights.
__global__ __launch_bounds__(256, 7)
void k_edge_fused(const ushort* __restrict__ h_bf,
                  const float* __restrict__ eattr,   // layer0 edge_attr fp32, else null
                  ushort* __restrict__ e_bf,         // padded 88-col bf16; in (L>0) / out
                  const int* __restrict__ ei,
                  const ushort* __restrict__ w1f, const ushort* __restrict__ w2f,
                  const ushort* __restrict__ v1f, const ushort* __restrict__ v2f,
                  const float* __restrict__ b1, const float* __restrict__ b2,
                  const float* __restrict__ g, const float* __restrict__ bb,
                  const float* __restrict__ vb1, const float* __restrict__ vb2,
                  float* __restrict__ agg, int store_e) {
    __shared__ __align__(16) ushort sCat[64 * 136]; // 17408 B
    __shared__ int s_idx[128];

    const int tid = threadIdx.x;
    const int e0 = blockIdx.x * 64;

    // ---- staging: s_idx + h gather + e convert, then ONE barrier ----
    if (tid < 128) s_idx[tid] = ei[(size_t)(tid >> 6) * N_EDGES + e0 + (tid & 63)];
#pragma unroll
    for (int i = 0; i < 2; i++) {
        int idx = tid + 256 * i;                     // < 384 = 64 rows * 6 chunks
        if (idx < 384) {
            int row = idx / 6, part = idx - row * 6; // part 0-2: src, 3-5: dst
            int node = ei[(size_t)(part >= 3) * N_EDGES + e0 + row];
            short8 v = *(const short8*)(h_bf + (size_t)node * 24 + (part % 3) * 8);
            *(short8*)(sCat + row * 136 + part * 8) = v;
        }
    }
    if (eattr) {
#pragma unroll
        for (int i = 0; i < 6; i++) {
            int u = tid + 256 * i;                   // < 1344 = 64 rows * 21 f32x4
            if (u < 1344) {
                int row = u / 21, c4 = u - row * 21;
                f32x4 v = *(const f32x4*)(eattr + (size_t)(e0 + row) * 84 + c4 * 4);
                bfx4 w;
                w[0] = (short)f2bf(v[0]); w[1] = (short)f2bf(v[1]);
                w[2] = (short)f2bf(v[2]); w[3] = (short)f2bf(v[3]);
                *(bfx4*)(sCat + row * 136 + 48 + c4 * 4) = w;
            }
        }
        // zero pad cols 132-135 (64 rows * 4 = 256)
        sCat[(tid >> 2) * 136 + 132 + (tid & 3)] = 0;
    } else {
#pragma unroll
        for (int i = 0; i < 3; i++) {
            int u = tid + 256 * i;                   // < 704 = 64 rows * 11 short8
            if (u < 704) {
                int row = u / 11, c8 = u - row * 11; // e_bf cols 84-87 are zeros -> pad ok
                *(short8*)(sCat + row * 136 + 48 + c8 * 8) =
                    *(const short8*)(e_bf + (size_t)(e0 + row) * 88 + c8 * 8);
            }
        }
    }
    __syncthreads();                                 // the only barrier

    const int lane = tid & 63, wave = tid >> 6;      // wave 0..3
    const int quad = lane >> 4, l15 = lane & 15;
    const int cbase = quad * 8;
    const int rA = wave * 16 + l15;                  // A-frag row (wave-private)

    // ---- GEMM1: t1 = cat @ w1 (A from LDS), two 3-nt passes (12 acc regs) ----
#pragma unroll
    for (int half = 0; half < 2; half++) {
        f32x4 acc[3];
#pragma unroll
        for (int n = 0; n < 3; n++) acc[n] = (f32x4)0.f;
#pragma unroll
        for (int kt = 0; kt < 5; kt++) {
            int c = kt * 32 + cbase; if (c > 128) c = 128;  // clamped -> zero weights
            short8 a = *(const short8*)(sCat + rA * 136 + c);
            const short8* bp = (const short8*)w1f + kt * 6 * 64 + half * 3 * 64 + lane;
#pragma unroll
            for (int n = 0; n < 3; n++) {
                short8 b = bp[n * 64];
                acc[n] = __builtin_amdgcn_mfma_f32_16x16x32_bf16(a, b, acc[n], 0, 0, 0);
            }
        }
        // gelu -> t1 over sCat e-region (cols 48-135, wave-private rows; pads exact 0)
#pragma unroll
        for (int n = 0; n < 3; n++) {
            int col = (half * 3 + n) * 16 + l15;
            float bv = (col < EDGE_DIM) ? b1[col] : 0.f;
#pragma unroll
            for (int r = 0; r < 4; r++) {
                int row = wave * 16 + quad * 4 + r;
                if (col < 88) sCat[row * 136 + 48 + col] = f2bf(gelu_exact(acc[n][r] + bv));
            }
        }
    }

    // ---- GEMM2: t1 @ w2 (wave-private, no barrier) ----
    f32x4 acc2[6];
#pragma unroll
    for (int nt = 0; nt < 6; nt++) acc2[nt] = (f32x4)0.f;
#pragma unroll
    for (int kt = 0; kt < 3; kt++) {
        int c = kt * 32 + cbase; if (c > 80) c = 80;
        short8 a = *(const short8*)(sCat + rA * 136 + 48 + c);
        const short8* bp = (const short8*)w2f + kt * 6 * 64 + lane;
#pragma unroll
        for (int nt = 0; nt < 6; nt++) {
            short8 b = bp[nt * 64];
            acc2[nt] = __builtin_amdgcn_mfma_f32_16x16x32_bf16(a, b, acc2[nt], 0, 0, 0);
        }
    }

    // ---- bias + residual + LayerNorm -> e_new back over sCat cols 48-131 ----
#pragma unroll
    for (int r = 0; r < 4; r++) {
        int row = wave * 16 + quad * 4 + r;
        long rg = e0 + row;
        float vv[6];
        float ss = 0.f, qq = 0.f;
#pragma unroll
        for (int nt = 0; nt < 6; nt++) {
            int col = nt * 16 + l15;
            float v = 0.f;
            if (col < EDGE_DIM) {
                v = acc2[nt][r] + b2[col];
                v += eattr ? eattr[rg * 84 + col] : bf2f(e_bf[rg * 88 + col]);
            }
            vv[nt] = v; ss += v; qq = fmaf(v, v, qq);
        }
        ss += __shfl_xor(ss, 1); ss += __shfl_xor(ss, 2);
        ss += __shfl_xor(ss, 4); ss += __shfl_xor(ss, 8);
        qq += __shfl_xor(qq, 1); qq += __shfl_xor(qq, 2);
        qq += __shfl_xor(qq, 4); qq += __shfl_xor(qq, 8);
        float mean = ss * (1.f / EDGE_DIM);
        float var  = qq * (1.f / EDGE_DIM) - mean * mean;
        float rstd = rsqrtf(var + LN_EPS);
#pragma unroll
        for (int nt = 0; nt < 6; nt++) {
            int col = nt * 16 + l15;
            if (col < EDGE_DIM)
                sCat[row * 136 + 48 + col] = f2bf((vv[nt] - mean) * rstd * g[col] + bb[col]);
        }
    }

    // ---- GEMM_V1: [hs|hd|e_new] @ v1 (full cat row from LDS again) ----
    f32x4 av[2];
#pragma unroll
    for (int nt = 0; nt < 2; nt++) av[nt] = (f32x4)0.f;
#pragma unroll
    for (int kt = 0; kt < 5; kt++) {
        int c = kt * 32 + cbase; if (c > 128) c = 128;
        short8 a = *(const short8*)(sCat + rA * 136 + c);
        const short8* bp = (const short8*)v1f + kt * 2 * 64 + lane;
#pragma unroll
        for (int nt = 0; nt < 2; nt++) {
            short8 b = bp[nt * 64];
            av[nt] = __builtin_amdgcn_mfma_f32_16x16x32_bf16(a, b, av[nt], 0, 0, 0);
        }
    }
    // gelu -> t_v into sCat cols 0-31 (hs/hd dead after V1; wave-private rows)
#pragma unroll
    for (int nt = 0; nt < 2; nt++) {
        int col = nt * 16 + l15;
        float bv = (col < HIDDEN) ? vb1[col] : 0.f;
#pragma unroll
        for (int r = 0; r < 4; r++) {
            int row = wave * 16 + quad * 4 + r;
            sCat[row * 136 + col] = f2bf(gelu_exact(av[nt][r] + bv));
        }
    }

    // ---- GEMM_V2: t_v @ v2 ----
    f32x4 av2[2];
#pragma unroll
    for (int nt = 0; nt < 2; nt++) av2[nt] = (f32x4)0.f;
    {
        short8 a = *(const short8*)(sCat + (size_t)rA * 136 + cbase);
        const short8* bp = (const short8*)v2f + lane;
#pragma unroll
        for (int nt = 0; nt < 2; nt++) {
            short8 b = bp[nt * 64];
            av2[nt] = __builtin_amdgcn_mfma_f32_16x16x32_bf16(a, b, av2[nt], 0, 0, 0);
        }
    }
    // scatter-add m into agg
#pragma unroll
    for (int nt = 0; nt < 2; nt++) {
        int col = nt * 16 + l15;
        if (col < HIDDEN) {
            float bv = vb2[col];
#pragma unroll
            for (int r = 0; r < 4; r++) {
                int row = wave * 16 + quad * 4 + r;
                int d = s_idx[64 + row];
                atomicAdd(&agg[(size_t)d * HIDDEN + col], av2[nt][r] + bv);
            }
        }
    }

    // ---- store e_new (88-col bf16), wave-private rows, no barrier ----
    if (store_e) {
        const uint* sU = (const uint*)sCat;          // pitch 68 dwords
        uint* dst32 = (uint*)e_bf;                   // pitch 44 dwords
#pragma unroll
        for (int i = 0; i < 11; i++) {
            int idx = lane + 64 * i;                 // < 704 = 16 rows * 44 dwords
            int rl = idx / 44, d = idx - rl * 44;
            int row = wave * 16 + rl;
            dst32[(size_t)(e0 + row) * 44 + d] = sU[row * 68 + 24 + d];
        }
    }
}

// ---------------- node update: h = LN(h + agg/counts) ----------------
__global__ void k_node_up(float* __restrict__ h, ushort* __restrict__ h_bf,
                          const float* __restrict__ agg,
                          const int* __restrict__ cnt,
                          const float* __restrict__ g, const float* __restrict__ b) {
    int n = blockIdx.x * blockDim.x + threadIdx.x;
    if (n >= N_NODES) return;
    int c = cnt[n]; if (c < 1) c = 1;
    float inv = 1.0f / (float)c;
    float v[HIDDEN];
    float s = 0.f;
#pragma unroll
    for (int j = 0; j < HIDDEN; j++) {
        v[j] = h[(size_t)n * HIDDEN + j] + agg[(size_t)n * HIDDEN + j] * inv;
        s += v[j];
    }
    float mean = s * (1.f / HIDDEN);
    float sq = 0.f;
#pragma unroll
    for (int j = 0; j < HIDDEN; j++) { float d = v[j] - mean; sq = fmaf(d, d, sq); }
    float rstd = rsqrtf(sq * (1.f / HIDDEN) + LN_EPS);
#pragma unroll
    for (int j = 0; j < HIDDEN; j++) {
        float o = (v[j] - mean) * rstd * g[j] + b[j];
        h[(size_t)n * HIDDEN + j] = o;
        h_bf[(size_t)n * HIDDEN + j] = f2bf(o);
    }
}

// ---------------- final: out = mu + intrinsic + context(h) ----------------
__global__ void k_final(const float* __restrict__ h, const float* __restrict__ intr,
                        const float* __restrict__ ch_w1, const float* __restrict__ ch_b1,
                        const float* __restrict__ ch_w2, const float* __restrict__ ch_b2,
                        const float* __restrict__ mu, float* __restrict__ out) {
    int n = blockIdx.x * blockDim.x + threadIdx.x;
    if (n >= N_NODES) return;
    float hv[HIDDEN];
#pragma unroll
    for (int j = 0; j < HIDDEN; j++) hv[j] = h[(size_t)n * HIDDEN + j];
    float acc = ch_b2[0];
    for (int j = 0; j < HEAD_HIDDEN; j++) {
        float t = ch_b1[j];
#pragma unroll
        for (int k = 0; k < HIDDEN; k++) t = fmaf(hv[k], ch_w1[k * HEAD_HIDDEN + j], t);
        acc = fmaf(gelu_exact(t), ch_w2[j], acc);
    }
    out[n] = mu[0] + intr[n] + acc;
}

extern "C" void kernel_launch(void* const* d_in, const int* in_sizes, int n_in,
                              void* d_out, int out_size, void* d_ws, size_t ws_size,
                              hipStream_t stream) {
    const float* x        = (const float*)d_in[0];
    const float* edge_attr= (const float*)d_in[1];
    const float* node_w   = (const float*)d_in[2];
    const float* node_b   = (const float*)d_in[3];
    const float* ih_w1    = (const float*)d_in[4];
    const float* ih_b1    = (const float*)d_in[5];
    const float* ih_w2    = (const float*)d_in[6];
    const float* ih_b2    = (const float*)d_in[7];
    const float* pe_w1    = (const float*)d_in[8];
    const float* pe_b1    = (const float*)d_in[9];
    const float* pe_w2    = (const float*)d_in[10];
    const float* pe_b2    = (const float*)d_in[11];
    const float* pv_w1    = (const float*)d_in[12];
    const float* pv_b1    = (const float*)d_in[13];
    const float* pv_w2    = (const float*)d_in[14];
    const float* pv_b2    = (const float*)d_in[15];
    const float* ne_g     = (const float*)d_in[16];
    const float* ne_b     = (const float*)d_in[17];
    const float* nv_g     = (const float*)d_in[18];
    const float* nv_b     = (const float*)d_in[19];
    const float* ch_w1    = (const float*)d_in[20];
    const float* ch_b1    = (const float*)d_in[21];
    const float* ch_w2    = (const float*)d_in[22];
    const float* ch_b2    = (const float*)d_in[23];
    const float* mu       = (const float*)d_in[24];
    const int*   ei       = (const int*)d_in[25];

    char* ws = (char*)d_ws;
    float*  h    = (float*)ws;  ws += (size_t)N_NODES * HIDDEN * 4;
    float*  agg  = (float*)ws;  ws += (size_t)N_NODES * HIDDEN * 4;
    float*  intr = (float*)ws;  ws += (size_t)N_NODES * 4;
    int*    cnt  = (int*)ws;    ws += (size_t)N_NODES * 4;
    ushort* h_bf = (ushort*)ws; ws += (size_t)N_NODES * HIDDEN * 2;
    ushort* wp   = (ushort*)ws; ws += (size_t)61440 * 2;
    ws = (char*)(((size_t)ws + 255) & ~(size_t)255);
    ushort* e_bf = (ushort*)ws; ws += (size_t)N_EDGES * 88 * 2;   // padded 88 cols

    const ushort* we1[2] = { wp + 0 * 15360, wp + 1 * 15360 };
    const ushort* we2[2] = { wp + 30720 + 0 * 9216, wp + 30720 + 1 * 9216 };
    const ushort* wv1[2] = { wp + 49152 + 0 * 5120, wp + 49152 + 1 * 5120 };
    const ushort* wv2[2] = { wp + 59392 + 0 * 1024, wp + 59392 + 1 * 1024 };

    hipMemsetAsync(cnt, 0, (size_t)N_NODES * 4, stream);
    k_prep_w<<<240, 256, 0, stream>>>(pe_w1, pe_w2, pv_w1, pv_w2, wp);
    k_counts<<<(N_EDGES + 255) / 256, 256, 0, stream>>>(ei, cnt);
    k_node_in<<<(N_NODES + 255) / 256, 256, 0, stream>>>(
        x, node_w, node_b, ih_w1, ih_b1, ih_w2, ih_b2, h, h_bf, intr);

    const int eb = N_EDGES / 64;    // 12500, exact
    for (int L = 0; L < 2; L++) {
        hipMemsetAsync(agg, 0, (size_t)N_NODES * HIDDEN * 4, stream);
        k_edge_fused<<<eb, 256, 0, stream>>>(
            h_bf, (L == 0) ? edge_attr : (const float*)nullptr, e_bf, ei,
            we1[L], we2[L], wv1[L], wv2[L],
            pe_b1 + (size_t)L * EDGE_DIM, pe_b2 + (size_t)L * EDGE_DIM,
            ne_g + (size_t)L * EDGE_DIM, ne_b + (size_t)L * EDGE_DIM,
            pv_b1 + (size_t)L * HIDDEN, pv_b2 + (size_t)L * HIDDEN,
            agg, (L == 0) ? 1 : 0);
        k_node_up<<<(N_NODES + 255) / 256, 256, 0, stream>>>(
            h, h_bf, agg, cnt, nv_g + (size_t)L * HIDDEN, nv_b + (size_t)L * HIDDEN);
    }
    k_final<<<(N_NODES + 255) / 256, 256, 0, stream>>>(
        h, intr, ch_w1, ch_b1, ch_w2, ch_b2, mu, (float*)d_out);
}

// Round 6
// 932.055 us; speedup vs baseline: 1.3681x; 1.0118x over previous
//
#include <hip/hip_runtime.h>
#include <math.h>

#define N_NODES 100000
#define N_EDGES 800000
#define NODE_IN 32
#define EDGE_DIM 84
#define HIDDEN 24
#define HEAD_HIDDEN 20
#define CAT_DIM 132
#define LN_EPS 1e-5f

typedef __attribute__((ext_vector_type(8))) short short8;
typedef __attribute__((ext_vector_type(4))) short bfx4;
typedef __attribute__((ext_vector_type(4))) float f32x4;
typedef unsigned int uint;
typedef unsigned short ushort;

__device__ __forceinline__ float gelu_exact(float x) {
    return 0.5f * x * (1.0f + erff(x * 0.70710678118654752f));
}
__device__ __forceinline__ ushort f2bf(float f) {
    union { float f; uint u; } c; c.f = f;
    uint u = c.u;
    return (ushort)((u + 0x7fffu + ((u >> 16) & 1u)) >> 16);
}
__device__ __forceinline__ float bf2f(ushort s) {
    union { uint u; float f; } c; c.u = ((uint)s) << 16; return c.f;
}

// ---------------- weight pre-pack to MFMA-fragment-major bf16 ----------------
// frag element (lane, j) = W[kt*32 + (lane>>4)*8 + j][nt*16 + (lane&15)], zero-padded.
// regions (frags of 512 bf16): pe_w1 2L*30 | pe_w2 2L*18 | pv_w1 2L*10 | pv_w2 2L*2
__global__ void k_prep_w(const float* __restrict__ pe_w1, const float* __restrict__ pe_w2,
                         const float* __restrict__ pv_w1, const float* __restrict__ pv_w2,
                         ushort* __restrict__ wp) {
    int idx = blockIdx.x * 256 + threadIdx.x;        // < 61440
    int j = idx & 7;
    int lane = (idx >> 3) & 63;
    int frag = idx >> 9;                             // 0..119
    int kq = (lane >> 4) * 8 + j;
    int n15 = lane & 15;
    float v = 0.f;
    if (frag < 60) {                                 // pe_w1: [L][5kt][6nt]
        int l = frag / 30, f = frag % 30;
        int kt = f / 6, nt = f % 6;
        int k = kt * 32 + kq, n = nt * 16 + n15;
        if (k < CAT_DIM && n < EDGE_DIM) v = pe_w1[(l * CAT_DIM + k) * EDGE_DIM + n];
    } else if (frag < 96) {                          // pe_w2: [L][3kt][6nt]
        int f2 = frag - 60; int l = f2 / 18, f = f2 % 18;
        int kt = f / 6, nt = f % 6;
        int k = kt * 32 + kq, n = nt * 16 + n15;
        if (k < EDGE_DIM && n < EDGE_DIM) v = pe_w2[(l * EDGE_DIM + k) * EDGE_DIM + n];
    } else if (frag < 116) {                         // pv_w1: [L][5kt][2nt]
        int f2 = frag - 96; int l = f2 / 10, f = f2 % 10;
        int kt = f / 2, nt = f % 2;
        int k = kt * 32 + kq, n = nt * 16 + n15;
        if (k < CAT_DIM && n < HIDDEN) v = pv_w1[(l * CAT_DIM + k) * HIDDEN + n];
    } else {                                         // pv_w2: [L][1kt][2nt]
        int f2 = frag - 116; int l = f2 / 2, nt = f2 % 2;
        int k = kq, n = nt * 16 + n15;
        if (k < HIDDEN && n < HIDDEN) v = pv_w2[(l * HIDDEN + k) * HIDDEN + n];
    }
    wp[idx] = f2bf(v);
}

// ---------------- node input projection + intrinsic head ----------------
__global__ void k_node_in(const float* __restrict__ x,
                          const float* __restrict__ node_w, const float* __restrict__ node_b,
                          const float* __restrict__ ih_w1, const float* __restrict__ ih_b1,
                          const float* __restrict__ ih_w2, const float* __restrict__ ih_b2,
                          float* __restrict__ h, ushort* __restrict__ h_bf,
                          float* __restrict__ intr) {
    int n = blockIdx.x * blockDim.x + threadIdx.x;
    if (n >= N_NODES) return;
    float xv[NODE_IN];
    const float4* xp = (const float4*)(x + (size_t)n * NODE_IN);
#pragma unroll
    for (int i = 0; i < NODE_IN / 4; i++) {
        float4 v = xp[i];
        xv[4*i+0] = v.x; xv[4*i+1] = v.y; xv[4*i+2] = v.z; xv[4*i+3] = v.w;
    }
    float hv[HIDDEN];
#pragma unroll
    for (int j = 0; j < HIDDEN; j++) hv[j] = node_b[j];
    for (int k = 0; k < NODE_IN; k++) {
        float xk = xv[k];
#pragma unroll
        for (int j = 0; j < HIDDEN; j++) hv[j] = fmaf(xk, node_w[k * HIDDEN + j], hv[j]);
    }
#pragma unroll
    for (int j = 0; j < HIDDEN; j++) {
        h[(size_t)n * HIDDEN + j] = hv[j];
        h_bf[(size_t)n * HIDDEN + j] = f2bf(hv[j]);
    }
    float acc = ih_b2[0];
    for (int j = 0; j < HEAD_HIDDEN; j++) {
        float t = ih_b1[j];
#pragma unroll
        for (int k = 0; k < HIDDEN; k++) t = fmaf(hv[k], ih_w1[k * HEAD_HIDDEN + j], t);
        acc = fmaf(gelu_exact(t), ih_w2[j], acc);
    }
    intr[n] = acc;
}

__global__ void k_counts(const int* __restrict__ ei, int* __restrict__ cnt) {
    int e = blockIdx.x * blockDim.x + threadIdx.x;
    if (e >= N_EDGES) return;
    atomicAdd(&cnt[ei[N_EDGES + e]], 1);
}

// ---------------- fused per-layer edge kernel: phi_e + LN + phi_v + scatter ----------------
// 64 edges/block, 4 waves x 16 rows, BARRIER-FREE: each wave stages its own 16 rows
// into its own sCat segment (no s_idx, no __syncthreads; intra-wave LDS ordering via
// lgkmcnt). LDS 17408B. GEMM1 split into two 3-nt passes; min-waves 7.
// sCat row layout (bf16, pitch 136): [hs 0-23 | hd 24-47 | e/t1/e_new 48-135];
// t_v overwrites cols 0-31 after V1. All clamped reads hit zero-padded weights.
__global__ __launch_bounds__(256, 7)
void k_edge_fused(const ushort* __restrict__ h_bf,
                  const float* __restrict__ eattr,   // layer0 edge_attr fp32, else null
                  ushort* __restrict__ e_bf,         // padded 88-col bf16; in (L>0) / out
                  const int* __restrict__ ei,
                  const ushort* __restrict__ w1f, const ushort* __restrict__ w2f,
                  const ushort* __restrict__ v1f, const ushort* __restrict__ v2f,
                  const float* __restrict__ b1, const float* __restrict__ b2,
                  const float* __restrict__ g, const float* __restrict__ bb,
                  const float* __restrict__ vb1, const float* __restrict__ vb2,
                  float* __restrict__ agg, int store_e) {
    __shared__ __align__(16) ushort sCat[64 * 136]; // 17408 B

    const int tid = threadIdx.x;
    const int e0 = blockIdx.x * 64;
    const int lane = tid & 63, wave = tid >> 6;      // wave 0..3
    const int w16 = wave * 16;

    // ---- wave-private staging of rows [w16, w16+16) — NO barrier ----
#pragma unroll
    for (int i = 0; i < 2; i++) {
        int c = lane + 64 * i;                       // < 96 = 16 rows * 6 chunks
        if (c < 96) {
            int row_l = c / 6, part = c - row_l * 6; // part 0-2: src, 3-5: dst
            int row = w16 + row_l;
            int node = ei[(size_t)(part >= 3) * N_EDGES + e0 + row];
            short8 v = *(const short8*)(h_bf + (size_t)node * 24 + (part % 3) * 8);
            *(short8*)(sCat + row * 136 + part * 8) = v;
        }
    }
    if (eattr) {
#pragma unroll
        for (int i = 0; i < 6; i++) {
            int u = lane + 64 * i;                   // < 336 = 16 rows * 21 f32x4
            if (u < 336) {
                int row_l = u / 21, c4 = u - row_l * 21;
                int row = w16 + row_l;
                f32x4 v = *(const f32x4*)(eattr + (size_t)(e0 + row) * 84 + c4 * 4);
                bfx4 wv;
                wv[0] = (short)f2bf(v[0]); wv[1] = (short)f2bf(v[1]);
                wv[2] = (short)f2bf(v[2]); wv[3] = (short)f2bf(v[3]);
                *(bfx4*)(sCat + row * 136 + 48 + c4 * 4) = wv;
            }
        }
        // zero pad cols 132-135 (16 rows * 4 = 64 per wave)
        sCat[(w16 + (lane >> 2)) * 136 + 132 + (lane & 3)] = 0;
    } else {
#pragma unroll
        for (int i = 0; i < 3; i++) {
            int u = lane + 64 * i;                   // < 176 = 16 rows * 11 short8
            if (u < 176) {
                int row_l = u / 11, c8 = u - row_l * 11; // e_bf cols 84-87 zero -> pad ok
                int row = w16 + row_l;
                *(short8*)(sCat + row * 136 + 48 + c8 * 8) =
                    *(const short8*)(e_bf + (size_t)(e0 + row) * 88 + c8 * 8);
            }
        }
    }
    // (intra-wave ds_write -> ds_read ordering enforced by compiler lgkmcnt)

    const int quad = lane >> 4, l15 = lane & 15;
    const int cbase = quad * 8;
    const int rA = w16 + l15;                        // A-frag row (wave-private)

    // ---- GEMM1: t1 = cat @ w1 (A from LDS), two 3-nt passes (12 acc regs) ----
#pragma unroll
    for (int half = 0; half < 2; half++) {
        f32x4 acc[3];
#pragma unroll
        for (int n = 0; n < 3; n++) acc[n] = (f32x4)0.f;
#pragma unroll
        for (int kt = 0; kt < 5; kt++) {
            int c = kt * 32 + cbase; if (c > 128) c = 128;  // clamped -> zero weights
            short8 a = *(const short8*)(sCat + rA * 136 + c);
            const short8* bp = (const short8*)w1f + kt * 6 * 64 + half * 3 * 64 + lane;
#pragma unroll
            for (int n = 0; n < 3; n++) {
                short8 b = bp[n * 64];
                acc[n] = __builtin_amdgcn_mfma_f32_16x16x32_bf16(a, b, acc[n], 0, 0, 0);
            }
        }
        // gelu -> t1 over sCat e-region (cols 48-135, wave-private rows; pads exact 0)
#pragma unroll
        for (int n = 0; n < 3; n++) {
            int col = (half * 3 + n) * 16 + l15;
            float bv = (col < EDGE_DIM) ? b1[col] : 0.f;
#pragma unroll
            for (int r = 0; r < 4; r++) {
                int row = w16 + quad * 4 + r;
                if (col < 88) sCat[row * 136 + 48 + col] = f2bf(gelu_exact(acc[n][r] + bv));
            }
        }
    }

    // ---- GEMM2: t1 @ w2 (wave-private, no barrier) ----
    f32x4 acc2[6];
#pragma unroll
    for (int nt = 0; nt < 6; nt++) acc2[nt] = (f32x4)0.f;
#pragma unroll
    for (int kt = 0; kt < 3; kt++) {
        int c = kt * 32 + cbase; if (c > 80) c = 80;
        short8 a = *(const short8*)(sCat + rA * 136 + 48 + c);
        const short8* bp = (const short8*)w2f + kt * 6 * 64 + lane;
#pragma unroll
        for (int nt = 0; nt < 6; nt++) {
            short8 b = bp[nt * 64];
            acc2[nt] = __builtin_amdgcn_mfma_f32_16x16x32_bf16(a, b, acc2[nt], 0, 0, 0);
        }
    }

    // ---- bias + residual + LayerNorm -> e_new back over sCat cols 48-131 ----
#pragma unroll
    for (int r = 0; r < 4; r++) {
        int row = w16 + quad * 4 + r;
        long rg = e0 + row;
        float vv[6];
        float ss = 0.f, qq = 0.f;
#pragma unroll
        for (int nt = 0; nt < 6; nt++) {
            int col = nt * 16 + l15;
            float v = 0.f;
            if (col < EDGE_DIM) {
                v = acc2[nt][r] + b2[col];
                v += eattr ? eattr[rg * 84 + col] : bf2f(e_bf[rg * 88 + col]);
            }
            vv[nt] = v; ss += v; qq = fmaf(v, v, qq);
        }
        ss += __shfl_xor(ss, 1); ss += __shfl_xor(ss, 2);
        ss += __shfl_xor(ss, 4); ss += __shfl_xor(ss, 8);
        qq += __shfl_xor(qq, 1); qq += __shfl_xor(qq, 2);
        qq += __shfl_xor(qq, 4); qq += __shfl_xor(qq, 8);
        float mean = ss * (1.f / EDGE_DIM);
        float var  = qq * (1.f / EDGE_DIM) - mean * mean;
        float rstd = rsqrtf(var + LN_EPS);
#pragma unroll
        for (int nt = 0; nt < 6; nt++) {
            int col = nt * 16 + l15;
            if (col < EDGE_DIM)
                sCat[row * 136 + 48 + col] = f2bf((vv[nt] - mean) * rstd * g[col] + bb[col]);
        }
    }

    // ---- GEMM_V1: [hs|hd|e_new] @ v1 (full cat row from LDS again) ----
    f32x4 av[2];
#pragma unroll
    for (int nt = 0; nt < 2; nt++) av[nt] = (f32x4)0.f;
#pragma unroll
    for (int kt = 0; kt < 5; kt++) {
        int c = kt * 32 + cbase; if (c > 128) c = 128;
        short8 a = *(const short8*)(sCat + rA * 136 + c);
        const short8* bp = (const short8*)v1f + kt * 2 * 64 + lane;
#pragma unroll
        for (int nt = 0; nt < 2; nt++) {
            short8 b = bp[nt * 64];
            av[nt] = __builtin_amdgcn_mfma_f32_16x16x32_bf16(a, b, av[nt], 0, 0, 0);
        }
    }
    // gelu -> t_v into sCat cols 0-31 (hs/hd dead after V1; wave-private rows)
#pragma unroll
    for (int nt = 0; nt < 2; nt++) {
        int col = nt * 16 + l15;
        float bv = (col < HIDDEN) ? vb1[col] : 0.f;
#pragma unroll
        for (int r = 0; r < 4; r++) {
            int row = w16 + quad * 4 + r;
            sCat[row * 136 + col] = f2bf(gelu_exact(av[nt][r] + bv));
        }
    }

    // ---- GEMM_V2: t_v @ v2 ----
    f32x4 av2[2];
#pragma unroll
    for (int nt = 0; nt < 2; nt++) av2[nt] = (f32x4)0.f;
    {
        short8 a = *(const short8*)(sCat + (size_t)rA * 136 + cbase);
        const short8* bp = (const short8*)v2f + lane;
#pragma unroll
        for (int nt = 0; nt < 2; nt++) {
            short8 b = bp[nt * 64];
            av2[nt] = __builtin_amdgcn_mfma_f32_16x16x32_bf16(a, b, av2[nt], 0, 0, 0);
        }
    }
    // scatter-add m into agg (dst re-read from ei, L2-hot)
    int dstv[4];
#pragma unroll
    for (int r = 0; r < 4; r++) dstv[r] = ei[(size_t)N_EDGES + e0 + w16 + quad * 4 + r];
#pragma unroll
    for (int nt = 0; nt < 2; nt++) {
        int col = nt * 16 + l15;
        if (col < HIDDEN) {
            float bv = vb2[col];
#pragma unroll
            for (int r = 0; r < 4; r++) {
                atomicAdd(&agg[(size_t)dstv[r] * HIDDEN + col], av2[nt][r] + bv);
            }
        }
    }

    // ---- store e_new (88-col bf16), wave-private rows, no barrier ----
    if (store_e) {
        const uint* sU = (const uint*)sCat;          // pitch 68 dwords
        uint* dst32 = (uint*)e_bf;                   // pitch 44 dwords
#pragma unroll
        for (int i = 0; i < 11; i++) {
            int idx = lane + 64 * i;                 // < 704 = 16 rows * 44 dwords
            int rl = idx / 44, d = idx - rl * 44;
            int row = w16 + rl;
            dst32[(size_t)(e0 + row) * 44 + d] = sU[row * 68 + 24 + d];
        }
    }
}

// ---------------- node update: h = LN(h + agg/counts) ----------------
__global__ void k_node_up(float* __restrict__ h, ushort* __restrict__ h_bf,
                          const float* __restrict__ agg,
                          const int* __restrict__ cnt,
                          const float* __restrict__ g, const float* __restrict__ b) {
    int n = blockIdx.x * blockDim.x + threadIdx.x;
    if (n >= N_NODES) return;
    int c = cnt[n]; if (c < 1) c = 1;
    float inv = 1.0f / (float)c;
    float v[HIDDEN];
    float s = 0.f;
#pragma unroll
    for (int j = 0; j < HIDDEN; j++) {
        v[j] = h[(size_t)n * HIDDEN + j] + agg[(size_t)n * HIDDEN + j] * inv;
        s += v[j];
    }
    float mean = s * (1.f / HIDDEN);
    float sq = 0.f;
#pragma unroll
    for (int j = 0; j < HIDDEN; j++) { float d = v[j] - mean; sq = fmaf(d, d, sq); }
    float rstd = rsqrtf(sq * (1.f / HIDDEN) + LN_EPS);
#pragma unroll
    for (int j = 0; j < HIDDEN; j++) {
        float o = (v[j] - mean) * rstd * g[j] + b[j];
        h[(size_t)n * HIDDEN + j] = o;
        h_bf[(size_t)n * HIDDEN + j] = f2bf(o);
    }
}

// ---------------- final: out = mu + intrinsic + context(h) ----------------
__global__ void k_final(const float* __restrict__ h, const float* __restrict__ intr,
                        const float* __restrict__ ch_w1, const float* __restrict__ ch_b1,
                        const float* __restrict__ ch_w2, const float* __restrict__ ch_b2,
                        const float* __restrict__ mu, float* __restrict__ out) {
    int n = blockIdx.x * blockDim.x + threadIdx.x;
    if (n >= N_NODES) return;
    float hv[HIDDEN];
#pragma unroll
    for (int j = 0; j < HIDDEN; j++) hv[j] = h[(size_t)n * HIDDEN + j];
    float acc = ch_b2[0];
    for (int j = 0; j < HEAD_HIDDEN; j++) {
        float t = ch_b1[j];
#pragma unroll
        for (int k = 0; k < HIDDEN; k++) t = fmaf(hv[k], ch_w1[k * HEAD_HIDDEN + j], t);
        acc = fmaf(gelu_exact(t), ch_w2[j], acc);
    }
    out[n] = mu[0] + intr[n] + acc;
}

extern "C" void kernel_launch(void* const* d_in, const int* in_sizes, int n_in,
                              void* d_out, int out_size, void* d_ws, size_t ws_size,
                              hipStream_t stream) {
    const float* x        = (const float*)d_in[0];
    const float* edge_attr= (const float*)d_in[1];
    const float* node_w   = (const float*)d_in[2];
    const float* node_b   = (const float*)d_in[3];
    const float* ih_w1    = (const float*)d_in[4];
    const float* ih_b1    = (const float*)d_in[5];
    const float* ih_w2    = (const float*)d_in[6];
    const float* ih_b2    = (const float*)d_in[7];
    const float* pe_w1    = (const float*)d_in[8];
    const float* pe_b1    = (const float*)d_in[9];
    const float* pe_w2    = (const float*)d_in[10];
    const float* pe_b2    = (const float*)d_in[11];
    const float* pv_w1    = (const float*)d_in[12];
    const float* pv_b1    = (const float*)d_in[13];
    const float* pv_w2    = (const float*)d_in[14];
    const float* pv_b2    = (const float*)d_in[15];
    const float* ne_g     = (const float*)d_in[16];
    const float* ne_b     = (const float*)d_in[17];
    const float* nv_g     = (const float*)d_in[18];
    const float* nv_b     = (const float*)d_in[19];
    const float* ch_w1    = (const float*)d_in[20];
    const float* ch_b1    = (const float*)d_in[21];
    const float* ch_w2    = (const float*)d_in[22];
    const float* ch_b2    = (const float*)d_in[23];
    const float* mu       = (const float*)d_in[24];
    const int*   ei       = (const int*)d_in[25];

    char* ws = (char*)d_ws;
    float*  h    = (float*)ws;  ws += (size_t)N_NODES * HIDDEN * 4;
    float*  agg  = (float*)ws;  ws += (size_t)N_NODES * HIDDEN * 4;
    float*  intr = (float*)ws;  ws += (size_t)N_NODES * 4;
    int*    cnt  = (int*)ws;    ws += (size_t)N_NODES * 4;
    ushort* h_bf = (ushort*)ws; ws += (size_t)N_NODES * HIDDEN * 2;
    ushort* wp   = (ushort*)ws; ws += (size_t)61440 * 2;
    ws = (char*)(((size_t)ws + 255) & ~(size_t)255);
    ushort* e_bf = (ushort*)ws; ws += (size_t)N_EDGES * 88 * 2;   // padded 88 cols

    const ushort* we1[2] = { wp + 0 * 15360, wp + 1 * 15360 };
    const ushort* we2[2] = { wp + 30720 + 0 * 9216, wp + 30720 + 1 * 9216 };
    const ushort* wv1[2] = { wp + 49152 + 0 * 5120, wp + 49152 + 1 * 5120 };
    const ushort* wv2[2] = { wp + 59392 + 0 * 1024, wp + 59392 + 1 * 1024 };

    hipMemsetAsync(cnt, 0, (size_t)N_NODES * 4, stream);
    k_prep_w<<<240, 256, 0, stream>>>(pe_w1, pe_w2, pv_w1, pv_w2, wp);
    k_counts<<<(N_EDGES + 255) / 256, 256, 0, stream>>>(ei, cnt);
    k_node_in<<<(N_NODES + 255) / 256, 256, 0, stream>>>(
        x, node_w, node_b, ih_w1, ih_b1, ih_w2, ih_b2, h, h_bf, intr);

    const int eb = N_EDGES / 64;    // 12500, exact
    for (int L = 0; L < 2; L++) {
        hipMemsetAsync(agg, 0, (size_t)N_NODES * HIDDEN * 4, stream);
        k_edge_fused<<<eb, 256, 0, stream>>>(
            h_bf, (L == 0) ? edge_attr : (const float*)nullptr, e_bf, ei,
            we1[L], we2[L], wv1[L], wv2[L],
            pe_b1 + (size_t)L * EDGE_DIM, pe_b2 + (size_t)L * EDGE_DIM,
            ne_g + (size_t)L * EDGE_DIM, ne_b + (size_t)L * EDGE_DIM,
            pv_b1 + (size_t)L * HIDDEN, pv_b2 + (size_t)L * HIDDEN,
            agg, (L == 0) ? 1 : 0);
        k_node_up<<<(N_NODES + 255) / 256, 256, 0, stream>>>(
            h, h_bf, agg, cnt, nv_g + (size_t)L * HIDDEN, nv_b + (size_t)L * HIDDEN);
    }
    k_final<<<(N_NODES + 255) / 256, 256, 0, stream>>>(
        h, intr, ch_w1, ch_b1, ch_w2, ch_b2, mu, (float*)d_out);
}